// Round 2
// baseline (739.612 us; speedup 1.0000x reference)
//
#include <hip/hip_runtime.h>

#define S_ 2048
#define F_ 512
#define I_ 1024
#define C_ 256

typedef float f4 __attribute__((ext_vector_type(4)));
typedef __bf16 bf8 __attribute__((ext_vector_type(8)));
typedef __bf16 bf4 __attribute__((ext_vector_type(4)));

__device__ __forceinline__ void gload_lds16(const __bf16* g, __bf16* l) {
  __builtin_amdgcn_global_load_lds(
      (const __attribute__((address_space(1))) void*)g,
      (__attribute__((address_space(3))) void*)l, 16, 0, 0);
}

__device__ __forceinline__ float fe_val(int f) {
  // fe[f] = exp(((f+1-additive)/2)*(8/F) - log(C/(2pi))) + additive*pi,
  // additive = (f+1)%2  (1 for even index f)
  const float PI_F = 3.14159265358979323846f;
  float additive = (f & 1) ? 0.0f : 1.0f;
  float fv = ((float)(f + 1) - additive) * 0.5f;
  fv = fv * (8.0f / (float)F_) - logf((float)C_ / (2.0f * PI_F));
  return expf(fv) + additive * PI_F;
}

// C[n][m] = sum_k A[m][k] * B'[k][n], activations position-major (n-major, k-contig).
// KW=3: K = 3*chan, k = t*chan + j, B'[k][n] = Bt[(n + t - 2)*ldb + j] (zero if row<0).
// Output written n-major (ldc = M) so it is the next GEMM's B input.
template <int KW, bool RELU, bool OBF16>
__global__ __launch_bounds__(256) void gemm_bt(
    const __bf16* __restrict__ Ab, const __bf16* __restrict__ Bb,
    void* __restrict__ Cb, const __bf16* __restrict__ zpage, int M, int K,
    int ldb, int chan, int PZ, long sAp, long sBp, long sBb, long sCz) {
  const int tid = threadIdx.x;
  const int z = blockIdx.z;
  const int p = z % PZ;
  const int bb = z / PZ;
  const __bf16* A = Ab + (long)p * sAp;
  const __bf16* Bt = Bb + (long)bb * sBb + (long)p * sBp;
  const int m0 = blockIdx.y * 128;
  const int n0 = blockIdx.x * 128;
  __shared__ __bf16 As[128 * 32];
  __shared__ __bf16 Bs[128 * 32];
  const int lane = tid & 63;
  const int wave = tid >> 6;
  const int wr = wave >> 1;
  const int wc = wave & 1;
  const int l15 = lane & 15;
  const int quad = lane >> 4;
  f4 acc[4][4] = {};
  const int cr = tid >> 2;         // tile row handled by this thread's 16B chunk
  const int cc = (tid & 3) * 8;    // element column within the 32-wide K tile

  for (int k0 = 0; k0 < K; k0 += 32) {
    const int t = (KW == 3) ? (k0 / chan) : 0;
    const int j0 = k0 - t * chan;
#pragma unroll
    for (int i = 0; i < 2; ++i) {
      const int r = i * 64 + cr;
      gload_lds16(A + (long)(m0 + r) * K + (k0 + cc),
                  As + ((i * 256 + (wave << 6)) << 3));
      const int rg = n0 + r + t - (KW - 1);
      const __bf16* gb = Bt + (long)rg * ldb + (j0 + cc);
      if (KW == 3 && rg < 0) gb = zpage;  // causal left-pad: zeros
      gload_lds16(gb, Bs + ((i * 256 + (wave << 6)) << 3));
    }
    __syncthreads();
    bf8 af[4], bfr[4];
#pragma unroll
    for (int mt = 0; mt < 4; ++mt)
      af[mt] = *(const bf8*)(As + ((wr * 64 + mt * 16 + l15) * 32 + quad * 8));
#pragma unroll
    for (int nt = 0; nt < 4; ++nt)
      bfr[nt] = *(const bf8*)(Bs + ((wc * 64 + nt * 16 + l15) * 32 + quad * 8));
#pragma unroll
    for (int mt = 0; mt < 4; ++mt)
#pragma unroll
      for (int nt = 0; nt < 4; ++nt)
        acc[mt][nt] = __builtin_amdgcn_mfma_f32_16x16x32_bf16(
            af[mt], bfr[nt], acc[mt][nt], 0, 0, 0);
    __syncthreads();
  }
#pragma unroll
  for (int mt = 0; mt < 4; ++mt) {
    const int m = m0 + wr * 64 + mt * 16 + quad * 4;
#pragma unroll
    for (int nt = 0; nt < 4; ++nt) {
      const int n = n0 + wc * 64 + nt * 16 + l15;
      f4 v = acc[mt][nt];
      if (RELU) {
#pragma unroll
        for (int q = 0; q < 4; ++q) v[q] = fmaxf(v[q], 0.0f);
      }
      if (OBF16) {
        bf4 o;
#pragma unroll
        for (int q = 0; q < 4; ++q) o[q] = (__bf16)v[q];
        *(bf4*)((__bf16*)Cb + (long)z * sCz + (long)n * M + m) = o;
      } else {
        *(f4*)((float*)Cb + (long)z * sCz + (long)n * M + m) = v;
      }
    }
  }
}

// f32 -> bf16 bulk convert (n % 4 == 0).
__global__ void k_cvt(const float* __restrict__ src, __bf16* __restrict__ dst,
                      long n) {
  long i = ((long)blockIdx.x * 256 + threadIdx.x) * 4;
  if (i >= n) return;
  const float4 v = *(const float4*)(src + i);
  bf4 o;
  o[0] = (__bf16)v.x;
  o[1] = (__bf16)v.y;
  o[2] = (__bf16)v.z;
  o[3] = (__bf16)v.w;
  *(bf4*)(dst + i) = o;
}

// Reorder+convert w1s (L,3,I,I,K) f32 -> W1r[l][p][i][t*I + j] bf16
// so conv2's A is k-contiguous (k = t*I + j).
__global__ void k_w1r(const float* __restrict__ w1, __bf16* __restrict__ W1r,
                      long total) {
  long idx = (long)blockIdx.x * 256 + threadIdx.x;
  if (idx >= total) return;
  float v = w1[idx];
  long t = idx % 3;
  long r2 = idx / 3;
  long j = r2 % I_;
  long r3 = r2 / I_;  // (l*3+p)*I + i
  W1r[r3 * (3 * I_) + t * I_ + j] = (__bf16)v;
}

// Gather embedding -> a/b state (fp32, position-major) + layer-0 h (bf16).
__global__ void k_embed(const int* __restrict__ inp,
                        const float* __restrict__ emb,
                        float* __restrict__ a_st, float* __restrict__ b_st,
                        __bf16* __restrict__ h) {
  const int bs = blockIdx.x;
  const int row = inp[bs];
  const float* e = emb + (long)row * (2 * F_);
  for (int f = threadIdx.x; f < F_; f += blockDim.x) {
    float av = e[f];
    float bv = e[F_ + f];
    a_st[(long)bs * F_ + f] = av;
    b_st[(long)bs * F_ + f] = bv;
    h[(long)bs * F_ + f] = (__bf16)(bv + fe_val(f));
  }
}

// Per (b,s) column: cumsum over channels, norm, EMA update; fuse next h / streams.
__global__ void k_cell(const float* __restrict__ Y3, float* __restrict__ a_st,
                       float* __restrict__ b_st, __bf16* __restrict__ outp,
                       int last) {
  const int tid = blockIdx.x * 64 + threadIdx.x;  // 0..4095
  const int s = tid & (S_ - 1);
  const int b = tid >> 11;
  const float* d = Y3 + ((long)(3 * b + 0) * S_ + s) * F_;
  const float* sc = Y3 + ((long)(3 * b + 1) * S_ + s) * F_;
  const float* sh = Y3 + ((long)(3 * b + 2) * S_ + s) * F_;
  float* ap = a_st + (long)tid * F_;
  float* bp = b_st + (long)tid * F_;
  const float inv_div = 1.0f / (float)(s + 1);
  float cum = 0.f, sum = 0.f, ssq = 0.f;
  for (int f = 0; f < F_; f += 4) {
    const float4 dv = *(const float4*)(d + f);
    const float4 scv = *(const float4*)(sc + f);
    const float4 shv = *(const float4*)(sh + f);
    float v;
    cum += dv.x; v = cum * inv_div * scv.x + shv.x; sum += v; ssq += v * v;
    cum += dv.y; v = cum * inv_div * scv.y + shv.y; sum += v; ssq += v * v;
    cum += dv.z; v = cum * inv_div * scv.z + shv.z; sum += v; ssq += v * v;
    cum += dv.w; v = cum * inv_div * scv.w + shv.w; sum += v; ssq += v * v;
  }
  const float mean = sum * (1.0f / (float)F_);
  float nsq = fmaxf(ssq - (float)F_ * mean * mean, 0.0f);
  const float denom = sqrtf(nsq) * 0.04419417382415922f + 1e-5f;  // *F^-0.5
  const float isc = 0.7071067811865476f / denom;  // INIT_SCALE / denom
  cum = 0.f;
  for (int f = 0; f < F_; f += 4) {
    const float4 dv = *(const float4*)(d + f);
    const float4 scv = *(const float4*)(sc + f);
    const float4 shv = *(const float4*)(sh + f);
    const float4 av = *(const float4*)(ap + f);
    const float4 bv = *(const float4*)(bp + f);
    float vv, cell, c;
    float4 an, bn;
    cum += dv.x; vv = cum * inv_div * scv.x + shv.x; cell = (vv - mean) * isc;
    c = 0.99f * av.x + 0.01f * cell; an.x = c; bn.x = bv.x + c;
    cum += dv.y; vv = cum * inv_div * scv.y + shv.y; cell = (vv - mean) * isc;
    c = 0.99f * av.y + 0.01f * cell; an.y = c; bn.y = bv.y + c;
    cum += dv.z; vv = cum * inv_div * scv.z + shv.z; cell = (vv - mean) * isc;
    c = 0.99f * av.z + 0.01f * cell; an.z = c; bn.z = bv.z + c;
    cum += dv.w; vv = cum * inv_div * scv.w + shv.w; cell = (vv - mean) * isc;
    c = 0.99f * av.w + 0.01f * cell; an.w = c; bn.w = bv.w + c;
    *(float4*)(ap + f) = an;
    *(float4*)(bp + f) = bn;
    if (!last) {
      __bf16* o = outp + (long)tid * F_ + f;
      o[0] = (__bf16)(bn.x + fe_val(f + 0));
      o[1] = (__bf16)(bn.y + fe_val(f + 1));
      o[2] = (__bf16)(bn.z + fe_val(f + 2));
      o[3] = (__bf16)(bn.w + fe_val(f + 3));
    } else {
      __bf16* o = outp + (long)tid * (2 * F_);
      o[f + 0] = (__bf16)an.x;
      o[f + 1] = (__bf16)an.y;
      o[f + 2] = (__bf16)an.z;
      o[f + 3] = (__bf16)an.w;
      o[F_ + f + 0] = (__bf16)bn.x;
      o[F_ + f + 1] = (__bf16)bn.y;
      o[F_ + f + 2] = (__bf16)bn.z;
      o[F_ + f + 3] = (__bf16)bn.w;
    }
  }
}

__global__ void k_nll(const float* __restrict__ logits,
                      const float* __restrict__ outb,
                      const int* __restrict__ tgt, float* __restrict__ acc) {
  const int tid = blockIdx.x * 64 + threadIdx.x;  // 0..4095
  const float* row = logits + (long)tid * C_;
  float mx = -3.0e38f;
  for (int c = 0; c < C_; c += 4) {
    const float4 lv = *(const float4*)(row + c);
    const float4 bv = *(const float4*)(outb + c);
    mx = fmaxf(mx, fmaxf(fmaxf(lv.x + bv.x, lv.y + bv.y),
                         fmaxf(lv.z + bv.z, lv.w + bv.w)));
  }
  float ss = 0.f;
  for (int c = 0; c < C_; c += 4) {
    const float4 lv = *(const float4*)(row + c);
    const float4 bv = *(const float4*)(outb + c);
    ss += expf(lv.x + bv.x - mx) + expf(lv.y + bv.y - mx) +
          expf(lv.z + bv.z - mx) + expf(lv.w + bv.w - mx);
  }
  const int t = tgt[tid];
  float nll = mx + logf(ss) - (row[t] + outb[t]);
#pragma unroll
  for (int off = 32; off > 0; off >>= 1) nll += __shfl_down(nll, off);
  if (threadIdx.x == 0) atomicAdd(acc, nll);
}

__global__ void k_final(const float* __restrict__ acc, float* __restrict__ out) {
  out[0] = acc[0] * (1.0f / 4096.0f);
}

extern "C" void kernel_launch(void* const* d_in, const int* in_sizes, int n_in,
                              void* d_out, int out_size, void* d_ws,
                              size_t ws_size, hipStream_t stream) {
  const int* inp = (const int*)d_in[0];
  const int* tgt = (const int*)d_in[1];
  const float* emb = (const float*)d_in[2];
  const float* w0s = (const float*)d_in[3];
  const float* w1s = (const float*)d_in[4];
  const float* w2s = (const float*)d_in[5];
  const float* out_w = (const float*)d_in[6];
  const float* out_b = (const float*)d_in[7];

  char* ws = (char*)d_ws;
  float* acc = (float*)(ws + 0);
  __bf16* zp = (__bf16*)(ws + 256);
  float* a_st = (float*)(ws + 4096);
  float* b_st = (float*)(ws + 8392704L);
  __bf16* h = (__bf16*)(ws + 16781312L);
  __bf16* Y1 = (__bf16*)(ws + 20975616L);     // [b][s][3I] bf16
  __bf16* Y2 = (__bf16*)(ws + 46141440L);     // [b*3+p][s][I] bf16
  float* Y3 = (float*)(ws + 71307264L);       // [b*3+p][s][F] f32
  __bf16* W1r = (__bf16*)(ws + 96473088L);    // [l][p][i][3I] bf16
  __bf16* streams = (__bf16*)(ws + 134221824L);
  float* logits = (float*)(ws + 142610432L);  // [b][s][C] f32
  __bf16* W0c = (__bf16*)(ws + 146804736L);   // w0s as bf16
  __bf16* W2c = (__bf16*)(ws + 153096192L);   // w2s as bf16
  __bf16* OWc = (__bf16*)(ws + 159387648L);   // out_w as bf16

  hipMemsetAsync(ws, 0, 4096, stream);  // acc + zero page
  k_cvt<<<3072, 256, 0, stream>>>(w0s, W0c, 3145728L);
  k_cvt<<<3072, 256, 0, stream>>>(w2s, W2c, 3145728L);
  k_cvt<<<256, 256, 0, stream>>>(out_w, OWc, 262144L);
  k_w1r<<<73728, 256, 0, stream>>>(w1s, W1r, 18874368L);
  k_embed<<<4096, 128, 0, stream>>>(inp, emb, a_st, b_st, h);

  for (int l = 0; l < 2; ++l) {
    // conv1: (3I x F) @ h  -> Y1, relu, bf16
    gemm_bt<1, true, true><<<dim3(16, 24, 2), 256, 0, stream>>>(
        W0c + (long)l * 1572864L, h, Y1, zp, 3072, 512, 512, 512, 1, 0L, 0L,
        1048576L, 6291456L);
    // conv2: causal k=3 (I x 3I) @ Y1 -> Y2, relu, bf16
    gemm_bt<3, true, true><<<dim3(16, 8, 6), 256, 0, stream>>>(
        W1r + (long)l * 9437184L, Y1, Y2, zp, 1024, 3072, 3072, 1024, 3,
        3145728L, 1024L, 6291456L, 2097152L);
    // conv3: (F x I) @ Y2 -> Y3, f32
    gemm_bt<1, false, false><<<dim3(16, 4, 6), 256, 0, stream>>>(
        W2c + (long)l * 1572864L, Y2, Y3, zp, 512, 1024, 1024, 1024, 3,
        524288L, 2097152L, 6291456L, 1048576L);
    k_cell<<<64, 64, 0, stream>>>(Y3, a_st, b_st, (l == 0) ? h : streams,
                                  (l == 1) ? 1 : 0);
  }

  // logits: (C x 2F) @ streams -> f32
  gemm_bt<1, false, false><<<dim3(16, 2, 2), 256, 0, stream>>>(
      OWc, streams, logits, zp, 256, 1024, 1024, 1024, 1, 0L, 0L, 2097152L,
      524288L);
  k_nll<<<64, 64, 0, stream>>>(logits, out_b, tgt, acc);
  k_final<<<1, 1, 0, stream>>>(acc, (float*)d_out);
}

// Round 3
// 577.605 us; speedup vs baseline: 1.2805x; 1.2805x over previous
//
#include <hip/hip_runtime.h>

#define S_ 2048
#define F_ 512
#define I_ 1024
#define C_ 256

typedef float f4 __attribute__((ext_vector_type(4)));
typedef __bf16 bf8 __attribute__((ext_vector_type(8)));
typedef __bf16 bf4 __attribute__((ext_vector_type(4)));

__device__ __forceinline__ void gload_lds16(const __bf16* g, __bf16* l) {
  __builtin_amdgcn_global_load_lds(
      (const __attribute__((address_space(1))) void*)g,
      (__attribute__((address_space(3))) void*)l, 16, 0, 0);
}

__device__ __forceinline__ float fe_val(int f) {
  // fe[f] = exp(((f+1-additive)/2)*(8/F) - log(C/(2pi))) + additive*pi,
  // additive = (f+1)%2  (1 for even index f)
  const float PI_F = 3.14159265358979323846f;
  float additive = (f & 1) ? 0.0f : 1.0f;
  float fv = ((float)(f + 1) - additive) * 0.5f;
  fv = fv * (8.0f / (float)F_) - logf((float)C_ / (2.0f * PI_F));
  return expf(fv) + additive * PI_F;
}

// C[n][m] = sum_k A[m][k] * B'[k][n], activations position-major (n-major, k-contig).
// KW=3: K = 3*1024, k = t*1024 + j, B'[k][n] = Bt[(n + t - 2)*ldb + j] (zero if row<0).
// Output written n-major (ldc = M) so it is the next GEMM's B input.
// LDS layout XOR-swizzled: row r's 8-elem chunk q lives at chunk slot q^((r>>1)&3)
// (loader fetches the permuted global chunk; global_load_lds lane->slot is fixed).
template <int KW, bool RELU, bool OBF16>
__global__ __launch_bounds__(256) void gemm_bt(
    const __bf16* __restrict__ Ab, const __bf16* __restrict__ Bb,
    void* __restrict__ Cb, const __bf16* __restrict__ zpage, int M, int K,
    int ldb, int PZ, long sAp, long sBp, long sBb, long sCz) {
  const int tid = threadIdx.x;
  const int z = blockIdx.z;
  const int p = z % PZ;
  const int bb = z / PZ;
  const __bf16* A = Ab + (long)p * sAp;
  const __bf16* Bt = Bb + (long)bb * sBb + (long)p * sBp;
  const int m0 = blockIdx.y * 128;
  const int n0 = blockIdx.x * 128;
  __shared__ __bf16 As[128 * 32];
  __shared__ __bf16 Bs[128 * 32];
  const int lane = tid & 63;
  const int wave = tid >> 6;
  const int wr = wave >> 1;
  const int wc = wave & 1;
  const int l15 = lane & 15;
  const int quad = lane >> 4;
  f4 acc[4][4] = {};
  const int cr = tid >> 2;  // tile row handled by this thread's 16B chunk
  // swizzled global chunk this thread stages (element offset in the 32-k tile)
  const int csw = (((tid & 3) ^ ((cr >> 1) & 3)) << 3);
  // read-side chunk offset: chunk quad of row l15 lives at quad^((l15>>1)&3)
  const int roff = ((quad ^ ((l15 >> 1) & 3)) << 3);

  for (int k0 = 0; k0 < K; k0 += 32) {
    const int t = (KW == 3) ? (k0 >> 10) : 0;
    const int j0 = (KW == 3) ? (k0 & 1023) : k0;
#pragma unroll
    for (int i = 0; i < 2; ++i) {
      const int r = i * 64 + cr;
      gload_lds16(A + (long)(m0 + r) * K + (k0 + csw),
                  As + ((i * 256 + (wave << 6)) << 3));
      const int rg = n0 + r + t - (KW - 1);
      const __bf16* gb = Bt + (long)rg * ldb + (j0 + csw);
      if (KW == 3 && rg < 0) gb = zpage;  // causal left-pad: zeros
      gload_lds16(gb, Bs + ((i * 256 + (wave << 6)) << 3));
    }
    __syncthreads();
    bf8 af[4], bfr[4];
#pragma unroll
    for (int mt = 0; mt < 4; ++mt)
      af[mt] = *(const bf8*)(As + (wr * 64 + mt * 16 + l15) * 32 + roff);
#pragma unroll
    for (int nt = 0; nt < 4; ++nt)
      bfr[nt] = *(const bf8*)(Bs + (wc * 64 + nt * 16 + l15) * 32 + roff);
#pragma unroll
    for (int mt = 0; mt < 4; ++mt)
#pragma unroll
      for (int nt = 0; nt < 4; ++nt)
        acc[mt][nt] = __builtin_amdgcn_mfma_f32_16x16x32_bf16(
            af[mt], bfr[nt], acc[mt][nt], 0, 0, 0);
    __syncthreads();
  }
#pragma unroll
  for (int mt = 0; mt < 4; ++mt) {
    const int m = m0 + wr * 64 + mt * 16 + quad * 4;
#pragma unroll
    for (int nt = 0; nt < 4; ++nt) {
      const int n = n0 + wc * 64 + nt * 16 + l15;
      f4 v = acc[mt][nt];
      if (RELU) {
#pragma unroll
        for (int q = 0; q < 4; ++q) v[q] = fmaxf(v[q], 0.0f);
      }
      if (OBF16) {
        bf4 o;
#pragma unroll
        for (int q = 0; q < 4; ++q) o[q] = (__bf16)v[q];
        *(bf4*)((__bf16*)Cb + (long)z * sCz + (long)n * M + m) = o;
      } else {
        *(f4*)((float*)Cb + (long)z * sCz + (long)n * M + m) = v;
      }
    }
  }
}

// f32 -> bf16 bulk convert (n % 4 == 0).
__global__ void k_cvt(const float* __restrict__ src, __bf16* __restrict__ dst,
                      long n) {
  long i = ((long)blockIdx.x * 256 + threadIdx.x) * 4;
  if (i >= n) return;
  const float4 v = *(const float4*)(src + i);
  bf4 o;
  o[0] = (__bf16)v.x;
  o[1] = (__bf16)v.y;
  o[2] = (__bf16)v.z;
  o[3] = (__bf16)v.w;
  *(bf4*)(dst + i) = o;
}

// Reorder+convert w1s (L,3,I,I,K) f32 -> W1r[l][p][i][t*I + j] bf16.
// Thread per (r3=(l*3+p)*I+i, j): reads 3 consecutive f32, 3 coalesced bf16
// store streams (one per t-plane).
__global__ void k_w1r(const float* __restrict__ w1, __bf16* __restrict__ W1r,
                      long total) {
  long idx = (long)blockIdx.x * 256 + threadIdx.x;
  if (idx >= total) return;
  long j = idx & (I_ - 1);
  long r3 = idx >> 10;
  const float* src = w1 + idx * 3;
  __bf16* dst = W1r + r3 * (3 * I_) + j;
  dst[0] = (__bf16)src[0];
  dst[I_] = (__bf16)src[1];
  dst[2 * I_] = (__bf16)src[2];
}

// Gather embedding -> a/b state (fp32, position-major) + layer-0 h (bf16).
__global__ void k_embed(const int* __restrict__ inp,
                        const float* __restrict__ emb,
                        float* __restrict__ a_st, float* __restrict__ b_st,
                        __bf16* __restrict__ h) {
  const int bs = blockIdx.x;
  const int row = inp[bs];
  const float* e = emb + (long)row * (2 * F_);
  for (int f = threadIdx.x; f < F_; f += blockDim.x) {
    float av = e[f];
    float bv = e[F_ + f];
    a_st[(long)bs * F_ + f] = av;
    b_st[(long)bs * F_ + f] = bv;
    h[(long)bs * F_ + f] = (__bf16)(bv + fe_val(f));
  }
}

// One wave per (b,s) column: shfl-scan cumsum over channels, butterfly stats,
// EMA update; fuse next-layer h / final streams. Single pass over memory.
__global__ __launch_bounds__(64) void k_cell(const float* __restrict__ Y3,
                                             float* __restrict__ a_st,
                                             float* __restrict__ b_st,
                                             __bf16* __restrict__ outp,
                                             int last) {
  const int col = blockIdx.x;  // b*2048 + s
  const int s = col & (S_ - 1);
  const int b = col >> 11;
  const int lane = threadIdx.x;
  const int f0 = lane * 8;
  const float* d = Y3 + ((long)(3 * b + 0) * S_ + s) * F_ + f0;
  const float* sc = Y3 + ((long)(3 * b + 1) * S_ + s) * F_ + f0;
  const float* sh = Y3 + ((long)(3 * b + 2) * S_ + s) * F_ + f0;
  float* ap = a_st + (long)col * F_ + f0;
  float* bp = b_st + (long)col * F_ + f0;
  const float inv_div = 1.0f / (float)(s + 1);

  const float4 d0 = *(const float4*)d;
  const float4 d1 = *(const float4*)(d + 4);
  const float4 sc0 = *(const float4*)sc;
  const float4 sc1 = *(const float4*)(sc + 4);
  const float4 sh0 = *(const float4*)sh;
  const float4 sh1 = *(const float4*)(sh + 4);

  // local inclusive prefix over this lane's 8 channels
  float c[8];
  c[0] = d0.x;
  c[1] = c[0] + d0.y;
  c[2] = c[1] + d0.z;
  c[3] = c[2] + d0.w;
  c[4] = c[3] + d1.x;
  c[5] = c[4] + d1.y;
  c[6] = c[5] + d1.z;
  c[7] = c[6] + d1.w;
  const float tot = c[7];
  float scan = tot;
#pragma unroll
  for (int off = 1; off < 64; off <<= 1) {
    float nb = __shfl_up(scan, off);
    if (lane >= off) scan += nb;
  }
  const float base = scan - tot;  // exclusive prefix of lane totals

  float v[8];
  v[0] = (base + c[0]) * inv_div * sc0.x + sh0.x;
  v[1] = (base + c[1]) * inv_div * sc0.y + sh0.y;
  v[2] = (base + c[2]) * inv_div * sc0.z + sh0.z;
  v[3] = (base + c[3]) * inv_div * sc0.w + sh0.w;
  v[4] = (base + c[4]) * inv_div * sc1.x + sh1.x;
  v[5] = (base + c[5]) * inv_div * sc1.y + sh1.y;
  v[6] = (base + c[6]) * inv_div * sc1.z + sh1.z;
  v[7] = (base + c[7]) * inv_div * sc1.w + sh1.w;

  float sum = 0.f, ssq = 0.f;
#pragma unroll
  for (int q = 0; q < 8; ++q) {
    sum += v[q];
    ssq += v[q] * v[q];
  }
#pragma unroll
  for (int off = 1; off < 64; off <<= 1) {
    sum += __shfl_xor(sum, off);
    ssq += __shfl_xor(ssq, off);
  }
  const float mean = sum * (1.0f / (float)F_);
  const float nsq = fmaxf(ssq - (float)F_ * mean * mean, 0.0f);
  const float denom = sqrtf(nsq) * 0.04419417382415922f + 1e-5f;  // *F^-0.5
  const float isc = 0.7071067811865476f / denom;  // INIT_SCALE / denom

  const float4 av0 = *(const float4*)ap;
  const float4 av1 = *(const float4*)(ap + 4);
  const float4 bv0 = *(const float4*)bp;
  const float4 bv1 = *(const float4*)(bp + 4);
  float an[8], bn[8];
  const float ai[8] = {av0.x, av0.y, av0.z, av0.w, av1.x, av1.y, av1.z, av1.w};
  const float bi[8] = {bv0.x, bv0.y, bv0.z, bv0.w, bv1.x, bv1.y, bv1.z, bv1.w};
#pragma unroll
  for (int q = 0; q < 8; ++q) {
    const float cell = (v[q] - mean) * isc;
    an[q] = 0.99f * ai[q] + 0.01f * cell;
    bn[q] = bi[q] + an[q];
  }
  *(float4*)ap = {an[0], an[1], an[2], an[3]};
  *(float4*)(ap + 4) = {an[4], an[5], an[6], an[7]};
  *(float4*)bp = {bn[0], bn[1], bn[2], bn[3]};
  *(float4*)(bp + 4) = {bn[4], bn[5], bn[6], bn[7]};
  if (!last) {
    bf8 o;
#pragma unroll
    for (int q = 0; q < 8; ++q) o[q] = (__bf16)(bn[q] + fe_val(f0 + q));
    *(bf8*)(outp + (long)col * F_ + f0) = o;
  } else {
    bf8 oa, ob;
#pragma unroll
    for (int q = 0; q < 8; ++q) {
      oa[q] = (__bf16)an[q];
      ob[q] = (__bf16)bn[q];
    }
    *(bf8*)(outp + (long)col * (2 * F_) + f0) = oa;
    *(bf8*)(outp + (long)col * (2 * F_) + F_ + f0) = ob;
  }
}

// One wave per (b,s) row of C=256 logits.
__global__ __launch_bounds__(256) void k_nll(const float* __restrict__ logits,
                                             const float* __restrict__ outb,
                                             const int* __restrict__ tgt,
                                             float* __restrict__ acc) {
  const int row = blockIdx.x * 4 + (threadIdx.x >> 6);
  const int lane = threadIdx.x & 63;
  const float* r = logits + (long)row * C_ + lane * 4;
  const float4 lv = *(const float4*)r;
  const float4 bv = *(const float4*)(outb + lane * 4);
  const float x0 = lv.x + bv.x, x1 = lv.y + bv.y, x2 = lv.z + bv.z,
              x3 = lv.w + bv.w;
  float mx = fmaxf(fmaxf(x0, x1), fmaxf(x2, x3));
#pragma unroll
  for (int off = 1; off < 64; off <<= 1) mx = fmaxf(mx, __shfl_xor(mx, off));
  float ss = expf(x0 - mx) + expf(x1 - mx) + expf(x2 - mx) + expf(x3 - mx);
#pragma unroll
  for (int off = 1; off < 64; off <<= 1) ss += __shfl_xor(ss, off);
  if (lane == 0) {
    const int t = tgt[row];
    const float nll = mx + logf(ss) - (logits[(long)row * C_ + t] + outb[t]);
    atomicAdd(acc, nll);
  }
}

__global__ void k_final(const float* __restrict__ acc, float* __restrict__ out) {
  out[0] = acc[0] * (1.0f / 4096.0f);
}

extern "C" void kernel_launch(void* const* d_in, const int* in_sizes, int n_in,
                              void* d_out, int out_size, void* d_ws,
                              size_t ws_size, hipStream_t stream) {
  const int* inp = (const int*)d_in[0];
  const int* tgt = (const int*)d_in[1];
  const float* emb = (const float*)d_in[2];
  const float* w0s = (const float*)d_in[3];
  const float* w1s = (const float*)d_in[4];
  const float* w2s = (const float*)d_in[5];
  const float* out_w = (const float*)d_in[6];
  const float* out_b = (const float*)d_in[7];

  char* ws = (char*)d_ws;
  float* acc = (float*)(ws + 0);
  __bf16* zp = (__bf16*)(ws + 256);
  float* a_st = (float*)(ws + 4096);
  float* b_st = (float*)(ws + 8392704L);
  __bf16* h = (__bf16*)(ws + 16781312L);
  __bf16* Y1 = (__bf16*)(ws + 20975616L);     // [b][s][3I] bf16
  __bf16* Y2 = (__bf16*)(ws + 46141440L);     // [b*3+p][s][I] bf16
  float* Y3 = (float*)(ws + 71307264L);       // [b*3+p][s][F] f32
  __bf16* W1r = (__bf16*)(ws + 96473088L);    // [l][p][i][3I] bf16
  __bf16* streams = (__bf16*)(ws + 134221824L);
  float* logits = (float*)(ws + 142610432L);  // [b][s][C] f32
  __bf16* W0c = (__bf16*)(ws + 146804736L);   // w0s as bf16
  __bf16* W2c = (__bf16*)(ws + 153096192L);   // w2s as bf16
  __bf16* OWc = (__bf16*)(ws + 159387648L);   // out_w as bf16

  hipMemsetAsync(ws, 0, 4096, stream);  // acc + zero page
  k_cvt<<<3072, 256, 0, stream>>>(w0s, W0c, 3145728L);
  k_cvt<<<3072, 256, 0, stream>>>(w2s, W2c, 3145728L);
  k_cvt<<<256, 256, 0, stream>>>(out_w, OWc, 262144L);
  k_w1r<<<24576, 256, 0, stream>>>(w1s, W1r, 6291456L);
  k_embed<<<4096, 128, 0, stream>>>(inp, emb, a_st, b_st, h);

  for (int l = 0; l < 2; ++l) {
    // conv1: (3I x F) @ h  -> Y1, relu, bf16
    gemm_bt<1, true, true><<<dim3(16, 24, 2), 256, 0, stream>>>(
        W0c + (long)l * 1572864L, h, Y1, zp, 3072, 512, 512, 1, 0L, 0L,
        1048576L, 6291456L);
    // conv2: causal k=3 (I x 3I) @ Y1 -> Y2, relu, bf16
    gemm_bt<3, true, true><<<dim3(16, 8, 6), 256, 0, stream>>>(
        W1r + (long)l * 9437184L, Y1, Y2, zp, 1024, 3072, 3072, 3, 3145728L,
        1024L, 6291456L, 2097152L);
    // conv3: (F x I) @ Y2 -> Y3, f32
    gemm_bt<1, false, false><<<dim3(16, 4, 6), 256, 0, stream>>>(
        W2c + (long)l * 1572864L, Y2, Y3, zp, 512, 1024, 1024, 3, 524288L,
        2097152L, 6291456L, 1048576L);
    k_cell<<<4096, 64, 0, stream>>>(Y3, a_st, b_st, (l == 0) ? h : streams,
                                    (l == 1) ? 1 : 0);
  }

  // logits: (C x 2F) @ streams -> f32
  gemm_bt<1, false, false><<<dim3(16, 2, 2), 256, 0, stream>>>(
      OWc, streams, logits, zp, 256, 1024, 1024, 1, 0L, 0L, 2097152L, 524288L);
  k_nll<<<1024, 256, 0, stream>>>(logits, out_b, tgt, acc);
  k_final<<<1, 1, 0, stream>>>(acc, (float*)d_out);
}

// Round 4
// 516.981 us; speedup vs baseline: 1.4306x; 1.1173x over previous
//
#include <hip/hip_runtime.h>

#define S_ 2048
#define F_ 512
#define I_ 1024
#define C_ 256

typedef float f4 __attribute__((ext_vector_type(4)));
typedef __bf16 bf8 __attribute__((ext_vector_type(8)));
typedef __bf16 bf4 __attribute__((ext_vector_type(4)));

__device__ __forceinline__ void gload_lds16(const __bf16* g, __bf16* l) {
  __builtin_amdgcn_global_load_lds(
      (const __attribute__((address_space(1))) void*)g,
      (__attribute__((address_space(3))) void*)l, 16, 0, 0);
}

__device__ __forceinline__ float fe_val(int f) {
  // fe[f] = exp(((f+1-additive)/2)*(8/F) - log(C/(2pi))) + additive*pi,
  // additive = (f+1)%2  (1 for even index f)
  const float PI_F = 3.14159265358979323846f;
  float additive = (f & 1) ? 0.0f : 1.0f;
  float fv = ((float)(f + 1) - additive) * 0.5f;
  fv = fv * (8.0f / (float)F_) - logf((float)C_ / (2.0f * PI_F));
  return expf(fv) + additive * PI_F;
}

// C[n][m] = sum_k A[m][k] * B'[k][n], activations position-major (n-major, k-contig).
// KW=3: K = 3*1024, k = t*1024 + j, B'[k][n] = Bt[(n + t - 2)*ldb + j] (zero if row<0).
// Output written n-major (ldc = M) so it is the next GEMM's B input.
// LDS XOR-swizzled: row r's 8-elem chunk q lives at slot q^((r>>1)&3).
// NTILE: 128 (2 B-staging passes, wave covers 64n) or 64 (1 pass, wave 32n).
template <int KW, bool RELU, bool OBF16, int NTILE>
__global__ __launch_bounds__(256) void gemm_bt(
    const __bf16* __restrict__ Ab, const __bf16* __restrict__ Bb,
    void* __restrict__ Cb, const __bf16* __restrict__ zpage, int M, int K,
    int ldb, int PZ, long sAp, long sBp, long sBb, long sCz) {
  constexpr int NF = NTILE / 32;  // n-frags per wave (span NTILE/2)
  const int tid = threadIdx.x;
  const int z = blockIdx.z;
  const int p = z % PZ;
  const int bb = z / PZ;
  const __bf16* A = Ab + (long)p * sAp;
  const __bf16* Bt = Bb + (long)bb * sBb + (long)p * sBp;
  const int m0 = blockIdx.y * 128;
  const int n0 = blockIdx.x * NTILE;
  __shared__ __bf16 As[128 * 32];
  __shared__ __bf16 Bs[NTILE * 32];
  const int lane = tid & 63;
  const int wave = tid >> 6;
  const int wr = wave >> 1;
  const int wc = wave & 1;
  const int l15 = lane & 15;
  const int quad = lane >> 4;
  f4 acc[4][NF] = {};
  const int cr = tid >> 2;  // tile row handled by this thread's 16B chunk
  const int csw = (((tid & 3) ^ ((cr >> 1) & 3)) << 3);      // staged chunk
  const int roff = ((quad ^ ((l15 >> 1) & 3)) << 3);         // read-side slot

  for (int k0 = 0; k0 < K; k0 += 32) {
    const int t = (KW == 3) ? (k0 >> 10) : 0;
    const int j0 = (KW == 3) ? (k0 & 1023) : k0;
#pragma unroll
    for (int i = 0; i < 2; ++i)
      gload_lds16(A + (long)(m0 + i * 64 + cr) * K + (k0 + csw),
                  As + ((i * 256 + (wave << 6)) << 3));
#pragma unroll
    for (int i = 0; i < NTILE / 64; ++i) {
      const int rg = n0 + i * 64 + cr + t - (KW - 1);
      const __bf16* gb = Bt + (long)rg * ldb + (j0 + csw);
      if (KW == 3 && rg < 0) gb = zpage;  // causal left-pad: zeros
      gload_lds16(gb, Bs + ((i * 256 + (wave << 6)) << 3));
    }
    __syncthreads();
    bf8 af[4], bfr[NF];
#pragma unroll
    for (int mt = 0; mt < 4; ++mt)
      af[mt] = *(const bf8*)(As + (wr * 64 + mt * 16 + l15) * 32 + roff);
#pragma unroll
    for (int nt = 0; nt < NF; ++nt)
      bfr[nt] =
          *(const bf8*)(Bs + (wc * (NTILE / 2) + nt * 16 + l15) * 32 + roff);
#pragma unroll
    for (int mt = 0; mt < 4; ++mt)
#pragma unroll
      for (int nt = 0; nt < NF; ++nt)
        acc[mt][nt] = __builtin_amdgcn_mfma_f32_16x16x32_bf16(
            af[mt], bfr[nt], acc[mt][nt], 0, 0, 0);
    __syncthreads();
  }
#pragma unroll
  for (int mt = 0; mt < 4; ++mt) {
    const int m = m0 + wr * 64 + mt * 16 + quad * 4;
#pragma unroll
    for (int nt = 0; nt < NF; ++nt) {
      const int n = n0 + wc * (NTILE / 2) + nt * 16 + l15;
      f4 v = acc[mt][nt];
      if (RELU) {
#pragma unroll
        for (int q = 0; q < 4; ++q) v[q] = fmaxf(v[q], 0.0f);
      }
      if (OBF16) {
        bf4 o;
#pragma unroll
        for (int q = 0; q < 4; ++q) o[q] = (__bf16)v[q];
        *(bf4*)((__bf16*)Cb + (long)z * sCz + (long)n * M + m) = o;
      } else {
        *(f4*)((float*)Cb + (long)z * sCz + (long)n * M + m) = v;
      }
    }
  }
}

__device__ __forceinline__ void cvt4(const float* __restrict__ s,
                                     __bf16* __restrict__ d, long T) {
  const long i = T * 4;
  const float4 v = *(const float4*)(s + i);
  bf4 o;
  o[0] = (__bf16)v.x;
  o[1] = (__bf16)v.y;
  o[2] = (__bf16)v.z;
  o[3] = (__bf16)v.w;
  *(bf4*)(d + i) = o;
}

// One dispatch: w0s/w2s/out_w f32->bf16, plus w1s reorder+convert.
// Segment sizes are multiples of 256 -> no intra-block divergence.
__global__ void k_prep(const float* __restrict__ w0, const float* __restrict__ w2,
                       const float* __restrict__ ow, const float* __restrict__ w1,
                       __bf16* __restrict__ W0c, __bf16* __restrict__ W2c,
                       __bf16* __restrict__ OWc, __bf16* __restrict__ W1r) {
  long T = (long)blockIdx.x * 256 + threadIdx.x;
  if (T < 786432L) {
    cvt4(w0, W0c, T);
    return;
  }
  T -= 786432L;
  if (T < 786432L) {
    cvt4(w2, W2c, T);
    return;
  }
  T -= 786432L;
  if (T < 65536L) {
    cvt4(ow, OWc, T);
    return;
  }
  T -= 65536L;
  // w1s (L,3,I,I,K=3) -> W1r[(l*3+p)*I+i][t*I + j]; thread per (r3,j)
  const long j = T & (I_ - 1);
  const long r3 = T >> 10;
  const float* src = w1 + T * 3;
  __bf16* dst = W1r + r3 * (3 * I_) + j;
  dst[0] = (__bf16)src[0];
  dst[I_] = (__bf16)src[1];
  dst[2 * I_] = (__bf16)src[2];
}

// One wave per (b,s): gather embedding -> a/b state (f32) + layer-0 h (bf16).
__global__ __launch_bounds__(64) void k_embed(const int* __restrict__ inp,
                                              const float* __restrict__ emb,
                                              float* __restrict__ a_st,
                                              float* __restrict__ b_st,
                                              __bf16* __restrict__ h) {
  const int col = blockIdx.x;
  const int lane = threadIdx.x;
  const int f0 = lane * 8;
  const float* e = emb + (long)inp[col] * (2 * F_);
  const float4 a0 = *(const float4*)(e + f0);
  const float4 a1 = *(const float4*)(e + f0 + 4);
  const float4 b0 = *(const float4*)(e + F_ + f0);
  const float4 b1 = *(const float4*)(e + F_ + f0 + 4);
  *(float4*)(a_st + (long)col * F_ + f0) = a0;
  *(float4*)(a_st + (long)col * F_ + f0 + 4) = a1;
  *(float4*)(b_st + (long)col * F_ + f0) = b0;
  *(float4*)(b_st + (long)col * F_ + f0 + 4) = b1;
  const float bb[8] = {b0.x, b0.y, b0.z, b0.w, b1.x, b1.y, b1.z, b1.w};
  bf8 o;
#pragma unroll
  for (int q = 0; q < 8; ++q) o[q] = (__bf16)(bb[q] + fe_val(f0 + q));
  *(bf8*)(h + (long)col * F_ + f0) = o;
}

// One wave per (b,s) column: shfl-scan cumsum over channels, butterfly stats,
// EMA update; fuse next-layer h / final streams. Single pass over memory.
__global__ __launch_bounds__(64) void k_cell(const float* __restrict__ Y3,
                                             float* __restrict__ a_st,
                                             float* __restrict__ b_st,
                                             __bf16* __restrict__ outp,
                                             int last) {
  const int col = blockIdx.x;  // b*2048 + s
  const int s = col & (S_ - 1);
  const int b = col >> 11;
  const int lane = threadIdx.x;
  const int f0 = lane * 8;
  const float* d = Y3 + ((long)(3 * b + 0) * S_ + s) * F_ + f0;
  const float* sc = Y3 + ((long)(3 * b + 1) * S_ + s) * F_ + f0;
  const float* sh = Y3 + ((long)(3 * b + 2) * S_ + s) * F_ + f0;
  float* ap = a_st + (long)col * F_ + f0;
  float* bp = b_st + (long)col * F_ + f0;
  const float inv_div = 1.0f / (float)(s + 1);

  const float4 d0 = *(const float4*)d;
  const float4 d1 = *(const float4*)(d + 4);
  const float4 sc0 = *(const float4*)sc;
  const float4 sc1 = *(const float4*)(sc + 4);
  const float4 sh0 = *(const float4*)sh;
  const float4 sh1 = *(const float4*)(sh + 4);

  float c[8];
  c[0] = d0.x;
  c[1] = c[0] + d0.y;
  c[2] = c[1] + d0.z;
  c[3] = c[2] + d0.w;
  c[4] = c[3] + d1.x;
  c[5] = c[4] + d1.y;
  c[6] = c[5] + d1.z;
  c[7] = c[6] + d1.w;
  const float tot = c[7];
  float scan = tot;
#pragma unroll
  for (int off = 1; off < 64; off <<= 1) {
    float nb = __shfl_up(scan, off);
    if (lane >= off) scan += nb;
  }
  const float base = scan - tot;  // exclusive prefix of lane totals

  float v[8];
  v[0] = (base + c[0]) * inv_div * sc0.x + sh0.x;
  v[1] = (base + c[1]) * inv_div * sc0.y + sh0.y;
  v[2] = (base + c[2]) * inv_div * sc0.z + sh0.z;
  v[3] = (base + c[3]) * inv_div * sc0.w + sh0.w;
  v[4] = (base + c[4]) * inv_div * sc1.x + sh1.x;
  v[5] = (base + c[5]) * inv_div * sc1.y + sh1.y;
  v[6] = (base + c[6]) * inv_div * sc1.z + sh1.z;
  v[7] = (base + c[7]) * inv_div * sc1.w + sh1.w;

  float sum = 0.f, ssq = 0.f;
#pragma unroll
  for (int q = 0; q < 8; ++q) {
    sum += v[q];
    ssq += v[q] * v[q];
  }
#pragma unroll
  for (int off = 1; off < 64; off <<= 1) {
    sum += __shfl_xor(sum, off);
    ssq += __shfl_xor(ssq, off);
  }
  const float mean = sum * (1.0f / (float)F_);
  const float nsq = fmaxf(ssq - (float)F_ * mean * mean, 0.0f);
  const float denom = sqrtf(nsq) * 0.04419417382415922f + 1e-5f;  // *F^-0.5
  const float isc = 0.7071067811865476f / denom;  // INIT_SCALE / denom

  const float4 av0 = *(const float4*)ap;
  const float4 av1 = *(const float4*)(ap + 4);
  const float4 bv0 = *(const float4*)bp;
  const float4 bv1 = *(const float4*)(bp + 4);
  float an[8], bn[8];
  const float ai[8] = {av0.x, av0.y, av0.z, av0.w, av1.x, av1.y, av1.z, av1.w};
  const float bi[8] = {bv0.x, bv0.y, bv0.z, bv0.w, bv1.x, bv1.y, bv1.z, bv1.w};
#pragma unroll
  for (int q = 0; q < 8; ++q) {
    const float cell = (v[q] - mean) * isc;
    an[q] = 0.99f * ai[q] + 0.01f * cell;
    bn[q] = bi[q] + an[q];
  }
  *(float4*)ap = {an[0], an[1], an[2], an[3]};
  *(float4*)(ap + 4) = {an[4], an[5], an[6], an[7]};
  *(float4*)bp = {bn[0], bn[1], bn[2], bn[3]};
  *(float4*)(bp + 4) = {bn[4], bn[5], bn[6], bn[7]};
  if (!last) {
    bf8 o;
#pragma unroll
    for (int q = 0; q < 8; ++q) o[q] = (__bf16)(bn[q] + fe_val(f0 + q));
    *(bf8*)(outp + (long)col * F_ + f0) = o;
  } else {
    bf8 oa, ob;
#pragma unroll
    for (int q = 0; q < 8; ++q) {
      oa[q] = (__bf16)an[q];
      ob[q] = (__bf16)bn[q];
    }
    *(bf8*)(outp + (long)col * (2 * F_) + f0) = oa;
    *(bf8*)(outp + (long)col * (2 * F_) + F_ + f0) = ob;
  }
}

// Fused logits GEMM (full M=256, 64-position tile) + bias + softmax + NLL.
// Grid (32, 2): blockIdx.x = position tile, blockIdx.y = batch.
__global__ __launch_bounds__(256) void k_logits_nll(
    const __bf16* __restrict__ A, const __bf16* __restrict__ Bb,
    const float* __restrict__ outb, const int* __restrict__ tgt,
    float* __restrict__ acc) {
  __shared__ __bf16 As[256 * 32];
  __shared__ __bf16 Bs[64 * 32];
  __shared__ float lsm[64 * 256];
  const int tid = threadIdx.x;
  const int b = blockIdx.y;
  const int n0 = blockIdx.x * 64;
  const __bf16* Bt = Bb + (long)b * (S_ * 2 * F_) + (long)n0 * (2 * F_);
  const int lane = tid & 63;
  const int wave = tid >> 6;
  const int l15 = lane & 15;
  const int quad = lane >> 4;
  const int cr = tid >> 2;
  const int csw = (((tid & 3) ^ ((cr >> 1) & 3)) << 3);
  const int roff = ((quad ^ ((l15 >> 1) & 3)) << 3);
  f4 av[4][4] = {};
  for (int k0 = 0; k0 < 2 * F_; k0 += 32) {
#pragma unroll
    for (int i = 0; i < 4; ++i)
      gload_lds16(A + (long)(i * 64 + cr) * (2 * F_) + (k0 + csw),
                  As + ((i * 256 + (wave << 6)) << 3));
    gload_lds16(Bt + (long)cr * (2 * F_) + (k0 + csw),
                Bs + ((wave << 6) << 3));
    __syncthreads();
    bf8 af[4], bfr[4];
#pragma unroll
    for (int mt = 0; mt < 4; ++mt)
      af[mt] = *(const bf8*)(As + (wave * 64 + mt * 16 + l15) * 32 + roff);
#pragma unroll
    for (int nt = 0; nt < 4; ++nt)
      bfr[nt] = *(const bf8*)(Bs + (nt * 16 + l15) * 32 + roff);
#pragma unroll
    for (int mt = 0; mt < 4; ++mt)
#pragma unroll
      for (int nt = 0; nt < 4; ++nt)
        av[mt][nt] = __builtin_amdgcn_mfma_f32_16x16x32_bf16(af[mt], bfr[nt],
                                                             av[mt][nt], 0, 0, 0);
    __syncthreads();
  }
#pragma unroll
  for (int mt = 0; mt < 4; ++mt) {
    const int m = wave * 64 + mt * 16 + quad * 4;
#pragma unroll
    for (int nt = 0; nt < 4; ++nt) {
      const int pp = nt * 16 + l15;
      *(f4*)(lsm + pp * C_ + m) = av[mt][nt];
    }
  }
  __syncthreads();
  // softmax + nll: wave handles 16 positions, lane covers 4 classes
  const float4 bv = *(const float4*)(outb + lane * 4);
  float wsum = 0.f;
  for (int i = 0; i < 16; ++i) {
    const int pp = wave * 16 + i;
    const f4 lv = *(const f4*)(lsm + pp * C_ + lane * 4);
    const float x0 = lv[0] + bv.x, x1 = lv[1] + bv.y, x2 = lv[2] + bv.z,
                x3 = lv[3] + bv.w;
    float mx = fmaxf(fmaxf(x0, x1), fmaxf(x2, x3));
#pragma unroll
    for (int off = 1; off < 64; off <<= 1) mx = fmaxf(mx, __shfl_xor(mx, off));
    float ss = expf(x0 - mx) + expf(x1 - mx) + expf(x2 - mx) + expf(x3 - mx);
#pragma unroll
    for (int off = 1; off < 64; off <<= 1) ss += __shfl_xor(ss, off);
    if (lane == 0) {
      const int t = tgt[b * S_ + n0 + pp];
      wsum += mx + logf(ss) - (lsm[pp * C_ + t] + outb[t]);
    }
  }
  if (lane == 0) atomicAdd(acc, wsum);
}

__global__ void k_final(const float* __restrict__ acc, float* __restrict__ out) {
  out[0] = acc[0] * (1.0f / 4096.0f);
}

extern "C" void kernel_launch(void* const* d_in, const int* in_sizes, int n_in,
                              void* d_out, int out_size, void* d_ws,
                              size_t ws_size, hipStream_t stream) {
  const int* inp = (const int*)d_in[0];
  const int* tgt = (const int*)d_in[1];
  const float* emb = (const float*)d_in[2];
  const float* w0s = (const float*)d_in[3];
  const float* w1s = (const float*)d_in[4];
  const float* w2s = (const float*)d_in[5];
  const float* out_w = (const float*)d_in[6];
  const float* out_b = (const float*)d_in[7];

  char* ws = (char*)d_ws;
  float* acc = (float*)(ws + 0);
  __bf16* zp = (__bf16*)(ws + 256);
  float* a_st = (float*)(ws + 4096);
  float* b_st = (float*)(ws + 8392704L);
  __bf16* h = (__bf16*)(ws + 16781312L);
  __bf16* Y1 = (__bf16*)(ws + 20975616L);     // [b][s][3I] bf16
  __bf16* Y2 = (__bf16*)(ws + 46141440L);     // [b*3+p][s][I] bf16
  float* Y3 = (float*)(ws + 71307264L);       // [b*3+p][s][F] f32
  __bf16* W1r = (__bf16*)(ws + 96473088L);    // [l][p][i][3I] bf16
  __bf16* streams = (__bf16*)(ws + 134221824L);
  __bf16* W0c = (__bf16*)(ws + 146804736L);   // w0s as bf16
  __bf16* W2c = (__bf16*)(ws + 153096192L);   // w2s as bf16
  __bf16* OWc = (__bf16*)(ws + 159387648L);   // out_w as bf16

  hipMemsetAsync(ws, 0, 4096, stream);  // acc + zero page
  k_prep<<<30976, 256, 0, stream>>>(w0s, w2s, out_w, w1s, W0c, W2c, OWc, W1r);
  k_embed<<<4096, 64, 0, stream>>>(inp, emb, a_st, b_st, h);

  for (int l = 0; l < 2; ++l) {
    // conv1: (3I x F) @ h  -> Y1, relu, bf16
    gemm_bt<1, true, true, 128><<<dim3(16, 24, 2), 256, 0, stream>>>(
        W0c + (long)l * 1572864L, h, Y1, zp, 3072, 512, 512, 1, 0L, 0L,
        1048576L, 6291456L);
    // conv2: causal k=3 (I x 3I) @ Y1 -> Y2, relu, bf16
    gemm_bt<3, true, true, 128><<<dim3(16, 8, 6), 256, 0, stream>>>(
        W1r + (long)l * 9437184L, Y1, Y2, zp, 1024, 3072, 3072, 3, 3145728L,
        1024L, 6291456L, 2097152L);
    // conv3: (F x I) @ Y2 -> Y3, f32; 64-wide n-tiles for 768-block balance
    gemm_bt<1, false, false, 64><<<dim3(32, 4, 6), 256, 0, stream>>>(
        W2c + (long)l * 1572864L, Y2, Y3, zp, 512, 1024, 1024, 3, 524288L,
        2097152L, 6291456L, 1048576L);
    k_cell<<<4096, 64, 0, stream>>>(Y3, a_st, b_st, (l == 0) ? h : streams,
                                    (l == 1) ? 1 : 0);
  }

  k_logits_nll<<<dim3(32, 2), 256, 0, stream>>>(OWc, streams, out_b, tgt, acc);
  k_final<<<1, 1, 0, stream>>>(acc, (float*)d_out);
}

// Round 5
// 510.308 us; speedup vs baseline: 1.4493x; 1.0131x over previous
//
#include <hip/hip_runtime.h>

#define S_ 2048
#define F_ 512
#define I_ 1024
#define C_ 256

typedef float f4 __attribute__((ext_vector_type(4)));
typedef __bf16 bf8 __attribute__((ext_vector_type(8)));
typedef __bf16 bf4 __attribute__((ext_vector_type(4)));

__device__ __forceinline__ void gload_lds16(const __bf16* g, __bf16* l) {
  __builtin_amdgcn_global_load_lds(
      (const __attribute__((address_space(1))) void*)g,
      (__attribute__((address_space(3))) void*)l, 16, 0, 0);
}

__device__ __forceinline__ float fe_val(int f) {
  // fe[f] = exp(((f+1-additive)/2)*(8/F) - log(C/(2pi))) + additive*pi,
  // additive = (f+1)%2  (1 for even index f)
  const float PI_F = 3.14159265358979323846f;
  float additive = (f & 1) ? 0.0f : 1.0f;
  float fv = ((float)(f + 1) - additive) * 0.5f;
  fv = fv * (8.0f / (float)F_) - logf((float)C_ / (2.0f * PI_F));
  return expf(fv) + additive * PI_F;
}

// C[n][m] = sum_k A[m][k] * B'[k][n], activations position-major (n-major,
// k-contig). KW=3: k = t*1024 + j, B'[k][n] = Bt[(n + t - 2)*ldb + j] (0 if
// row<0; zero-page redirect is t-segment invariant). Output n-major (ldc=M).
// LDS XOR-swizzle: row r's 8-elem chunk q at slot q^((r>>1)&3).
// BK=64: two 32-k sub-panels per barrier pair -> 32 MFMA/barrier.
// K compile-time -> inner 16-iter loop unrolls, addresses fold to immediates.
template <int KW, bool RELU, bool OBF16, int NTILE, int K>
__global__ __launch_bounds__(256) void gemm_bt(
    const __bf16* __restrict__ Ab, const __bf16* __restrict__ Bb,
    void* __restrict__ Cb, const __bf16* __restrict__ zpage, int M, int ldb,
    int PZ, long sAp, long sBp, long sBb, long sCz) {
  constexpr int NF = NTILE / 32;          // n-frags per wave
  constexpr int TSEG = (KW == 3) ? 3 : 1; // t-segments
  constexpr int KSEG = K / TSEG;
  constexpr int NIT = KSEG / 64;          // BK=64 iters per segment
  const int tid = threadIdx.x;
  const int z = blockIdx.z;
  const int p = z % PZ;
  const int bb = z / PZ;
  const __bf16* A = Ab + (long)p * sAp;
  const __bf16* Bt = Bb + (long)bb * sBb + (long)p * sBp;
  const int m0 = blockIdx.y * 128;
  const int n0 = blockIdx.x * NTILE;
  __shared__ __bf16 As[2][128 * 32];
  __shared__ __bf16 Bs[2][NTILE * 32];
  const int lane = tid & 63;
  const int wave = tid >> 6;
  const int wr = wave >> 1;
  const int wc = wave & 1;
  const int l15 = lane & 15;
  const int quad = lane >> 4;
  f4 acc[4][NF] = {};
  const int cr = tid >> 2;  // tile row handled by this thread's 16B chunk
  const int csw = (((tid & 3) ^ ((cr >> 1) & 3)) << 3);  // staged chunk
  const int roff = ((quad ^ ((l15 >> 1) & 3)) << 3);     // read-side slot

  for (int t = 0; t < TSEG; ++t) {
    const __bf16* pA = A + (long)(m0 + cr) * K + (t * KSEG + csw);
    const __bf16* pB[NTILE / 64];
#pragma unroll
    for (int i = 0; i < NTILE / 64; ++i) {
      const int rg = n0 + i * 64 + cr + ((KW == 3) ? (t - 2) : 0);
      pB[i] = (KW == 3 && rg < 0) ? (zpage + csw) : (Bt + (long)rg * ldb + csw);
    }
#pragma unroll
    for (int it = 0; it < NIT; ++it) {
#pragma unroll
      for (int sub = 0; sub < 2; ++sub) {
#pragma unroll
        for (int i = 0; i < 2; ++i)
          gload_lds16(pA + ((long)i * 64 * K + it * 64 + sub * 32),
                      &As[sub][(i * 256 + wave * 64) * 8]);
#pragma unroll
        for (int i = 0; i < NTILE / 64; ++i)
          gload_lds16(pB[i] + (it * 64 + sub * 32),
                      &Bs[sub][(i * 256 + wave * 64) * 8]);
      }
      __syncthreads();
#pragma unroll
      for (int sub = 0; sub < 2; ++sub) {
        bf8 af[4], bfr[NF];
#pragma unroll
        for (int mt = 0; mt < 4; ++mt)
          af[mt] =
              *(const bf8*)(&As[sub][(wr * 64 + mt * 16 + l15) * 32 + roff]);
#pragma unroll
        for (int nt = 0; nt < NF; ++nt)
          bfr[nt] = *(const bf8*)(&Bs[sub][(wc * (NTILE / 2) + nt * 16 + l15) *
                                               32 +
                                           roff]);
#pragma unroll
        for (int mt = 0; mt < 4; ++mt)
#pragma unroll
          for (int nt = 0; nt < NF; ++nt)
            acc[mt][nt] = __builtin_amdgcn_mfma_f32_16x16x32_bf16(
                af[mt], bfr[nt], acc[mt][nt], 0, 0, 0);
      }
      __syncthreads();
    }
  }
#pragma unroll
  for (int mt = 0; mt < 4; ++mt) {
    const int m = m0 + wr * 64 + mt * 16 + quad * 4;
#pragma unroll
    for (int nt = 0; nt < NF; ++nt) {
      const int n = n0 + wc * (NTILE / 2) + nt * 16 + l15;
      f4 v = acc[mt][nt];
      if (RELU) {
#pragma unroll
        for (int q = 0; q < 4; ++q) v[q] = fmaxf(v[q], 0.0f);
      }
      if (OBF16) {
        bf4 o;
#pragma unroll
        for (int q = 0; q < 4; ++q) o[q] = (__bf16)v[q];
        *(bf4*)((__bf16*)Cb + (long)z * sCz + (long)n * M + m) = o;
      } else {
        *(f4*)((float*)Cb + (long)z * sCz + (long)n * M + m) = v;
      }
    }
  }
}

__device__ __forceinline__ void cvt4(const float* __restrict__ s,
                                     __bf16* __restrict__ d, long T) {
  const long i = T * 4;
  const float4 v = *(const float4*)(s + i);
  bf4 o;
  o[0] = (__bf16)v.x;
  o[1] = (__bf16)v.y;
  o[2] = (__bf16)v.z;
  o[3] = (__bf16)v.w;
  *(bf4*)(d + i) = o;
}

// One dispatch: w0s/w2s/out_w f32->bf16, plus w1s reorder+convert.
// Segment sizes are multiples of 256 -> no intra-block divergence.
__global__ void k_prep(const float* __restrict__ w0, const float* __restrict__ w2,
                       const float* __restrict__ ow, const float* __restrict__ w1,
                       __bf16* __restrict__ W0c, __bf16* __restrict__ W2c,
                       __bf16* __restrict__ OWc, __bf16* __restrict__ W1r) {
  long T = (long)blockIdx.x * 256 + threadIdx.x;
  if (T < 786432L) {
    cvt4(w0, W0c, T);
    return;
  }
  T -= 786432L;
  if (T < 786432L) {
    cvt4(w2, W2c, T);
    return;
  }
  T -= 786432L;
  if (T < 65536L) {
    cvt4(ow, OWc, T);
    return;
  }
  T -= 65536L;
  // w1s (L,3,I,I,K=3) -> W1r[(l*3+p)*I+i][t*I + j]; thread per (r3,j)
  const long j = T & (I_ - 1);
  const long r3 = T >> 10;
  const float* src = w1 + T * 3;
  __bf16* dst = W1r + r3 * (3 * I_) + j;
  dst[0] = (__bf16)src[0];
  dst[I_] = (__bf16)src[1];
  dst[2 * I_] = (__bf16)src[2];
}

// One wave per (b,s): gather embedding -> a/b state (f32) + layer-0 h (bf16).
__global__ __launch_bounds__(64) void k_embed(const int* __restrict__ inp,
                                              const float* __restrict__ emb,
                                              float* __restrict__ a_st,
                                              float* __restrict__ b_st,
                                              __bf16* __restrict__ h) {
  const int col = blockIdx.x;
  const int lane = threadIdx.x;
  const int f0 = lane * 8;
  const float* e = emb + (long)inp[col] * (2 * F_);
  const float4 a0 = *(const float4*)(e + f0);
  const float4 a1 = *(const float4*)(e + f0 + 4);
  const float4 b0 = *(const float4*)(e + F_ + f0);
  const float4 b1 = *(const float4*)(e + F_ + f0 + 4);
  *(float4*)(a_st + (long)col * F_ + f0) = a0;
  *(float4*)(a_st + (long)col * F_ + f0 + 4) = a1;
  *(float4*)(b_st + (long)col * F_ + f0) = b0;
  *(float4*)(b_st + (long)col * F_ + f0 + 4) = b1;
  const float bb[8] = {b0.x, b0.y, b0.z, b0.w, b1.x, b1.y, b1.z, b1.w};
  bf8 o;
#pragma unroll
  for (int q = 0; q < 8; ++q) o[q] = (__bf16)(bb[q] + fe_val(f0 + q));
  *(bf8*)(h + (long)col * F_ + f0) = o;
}

// One wave per (b,s) column: shfl-scan cumsum over channels, butterfly stats,
// EMA update; fuse next-layer h / final streams. Single pass over memory.
__global__ __launch_bounds__(64) void k_cell(const float* __restrict__ Y3,
                                             float* __restrict__ a_st,
                                             float* __restrict__ b_st,
                                             __bf16* __restrict__ outp,
                                             int last) {
  const int col = blockIdx.x;  // b*2048 + s
  const int s = col & (S_ - 1);
  const int b = col >> 11;
  const int lane = threadIdx.x;
  const int f0 = lane * 8;
  const float* d = Y3 + ((long)(3 * b + 0) * S_ + s) * F_ + f0;
  const float* sc = Y3 + ((long)(3 * b + 1) * S_ + s) * F_ + f0;
  const float* sh = Y3 + ((long)(3 * b + 2) * S_ + s) * F_ + f0;
  float* ap = a_st + (long)col * F_ + f0;
  float* bp = b_st + (long)col * F_ + f0;
  const float inv_div = 1.0f / (float)(s + 1);

  const float4 d0 = *(const float4*)d;
  const float4 d1 = *(const float4*)(d + 4);
  const float4 sc0 = *(const float4*)sc;
  const float4 sc1 = *(const float4*)(sc + 4);
  const float4 sh0 = *(const float4*)sh;
  const float4 sh1 = *(const float4*)(sh + 4);

  float c[8];
  c[0] = d0.x;
  c[1] = c[0] + d0.y;
  c[2] = c[1] + d0.z;
  c[3] = c[2] + d0.w;
  c[4] = c[3] + d1.x;
  c[5] = c[4] + d1.y;
  c[6] = c[5] + d1.z;
  c[7] = c[6] + d1.w;
  const float tot = c[7];
  float scan = tot;
#pragma unroll
  for (int off = 1; off < 64; off <<= 1) {
    float nb = __shfl_up(scan, off);
    if (lane >= off) scan += nb;
  }
  const float base = scan - tot;  // exclusive prefix of lane totals

  float v[8];
  v[0] = (base + c[0]) * inv_div * sc0.x + sh0.x;
  v[1] = (base + c[1]) * inv_div * sc0.y + sh0.y;
  v[2] = (base + c[2]) * inv_div * sc0.z + sh0.z;
  v[3] = (base + c[3]) * inv_div * sc0.w + sh0.w;
  v[4] = (base + c[4]) * inv_div * sc1.x + sh1.x;
  v[5] = (base + c[5]) * inv_div * sc1.y + sh1.y;
  v[6] = (base + c[6]) * inv_div * sc1.z + sh1.z;
  v[7] = (base + c[7]) * inv_div * sc1.w + sh1.w;

  float sum = 0.f, ssq = 0.f;
#pragma unroll
  for (int q = 0; q < 8; ++q) {
    sum += v[q];
    ssq += v[q] * v[q];
  }
#pragma unroll
  for (int off = 1; off < 64; off <<= 1) {
    sum += __shfl_xor(sum, off);
    ssq += __shfl_xor(ssq, off);
  }
  const float mean = sum * (1.0f / (float)F_);
  const float nsq = fmaxf(ssq - (float)F_ * mean * mean, 0.0f);
  const float denom = sqrtf(nsq) * 0.04419417382415922f + 1e-5f;  // *F^-0.5
  const float isc = 0.7071067811865476f / denom;  // INIT_SCALE / denom

  const float4 av0 = *(const float4*)ap;
  const float4 av1 = *(const float4*)(ap + 4);
  const float4 bv0 = *(const float4*)bp;
  const float4 bv1 = *(const float4*)(bp + 4);
  float an[8], bn[8];
  const float ai[8] = {av0.x, av0.y, av0.z, av0.w, av1.x, av1.y, av1.z, av1.w};
  const float bi[8] = {bv0.x, bv0.y, bv0.z, bv0.w, bv1.x, bv1.y, bv1.z, bv1.w};
#pragma unroll
  for (int q = 0; q < 8; ++q) {
    const float cell = (v[q] - mean) * isc;
    an[q] = 0.99f * ai[q] + 0.01f * cell;
    bn[q] = bi[q] + an[q];
  }
  *(float4*)ap = {an[0], an[1], an[2], an[3]};
  *(float4*)(ap + 4) = {an[4], an[5], an[6], an[7]};
  *(float4*)bp = {bn[0], bn[1], bn[2], bn[3]};
  *(float4*)(bp + 4) = {bn[4], bn[5], bn[6], bn[7]};
  if (!last) {
    bf8 o;
#pragma unroll
    for (int q = 0; q < 8; ++q) o[q] = (__bf16)(bn[q] + fe_val(f0 + q));
    *(bf8*)(outp + (long)col * F_ + f0) = o;
  } else {
    bf8 oa, ob;
#pragma unroll
    for (int q = 0; q < 8; ++q) {
      oa[q] = (__bf16)an[q];
      ob[q] = (__bf16)bn[q];
    }
    *(bf8*)(outp + (long)col * (2 * F_) + f0) = oa;
    *(bf8*)(outp + (long)col * (2 * F_) + F_ + f0) = ob;
  }
}

// Fused logits GEMM (full M=256, 64-position tile) + bias + softmax + NLL.
// Grid (32, 2): blockIdx.x = position tile, blockIdx.y = batch.
__global__ __launch_bounds__(256) void k_logits_nll(
    const __bf16* __restrict__ A, const __bf16* __restrict__ Bb,
    const float* __restrict__ outb, const int* __restrict__ tgt,
    float* __restrict__ acc) {
  __shared__ __bf16 As[256 * 32];
  __shared__ __bf16 Bs[64 * 32];
  __shared__ float lsm[64 * 256];
  const int tid = threadIdx.x;
  const int b = blockIdx.y;
  const int n0 = blockIdx.x * 64;
  const __bf16* Bt = Bb + (long)b * (S_ * 2 * F_) + (long)n0 * (2 * F_);
  const int lane = tid & 63;
  const int wave = tid >> 6;
  const int l15 = lane & 15;
  const int quad = lane >> 4;
  const int cr = tid >> 2;
  const int csw = (((tid & 3) ^ ((cr >> 1) & 3)) << 3);
  const int roff = ((quad ^ ((l15 >> 1) & 3)) << 3);
  f4 av[4][4] = {};
  for (int k0 = 0; k0 < 2 * F_; k0 += 32) {
#pragma unroll
    for (int i = 0; i < 4; ++i)
      gload_lds16(A + (long)(i * 64 + cr) * (2 * F_) + (k0 + csw),
                  As + ((i * 256 + (wave << 6)) << 3));
    gload_lds16(Bt + (long)cr * (2 * F_) + (k0 + csw),
                Bs + ((wave << 6) << 3));
    __syncthreads();
    bf8 af[4], bfr[4];
#pragma unroll
    for (int mt = 0; mt < 4; ++mt)
      af[mt] = *(const bf8*)(As + (wave * 64 + mt * 16 + l15) * 32 + roff);
#pragma unroll
    for (int nt = 0; nt < 4; ++nt)
      bfr[nt] = *(const bf8*)(Bs + (nt * 16 + l15) * 32 + roff);
#pragma unroll
    for (int mt = 0; mt < 4; ++mt)
#pragma unroll
      for (int nt = 0; nt < 4; ++nt)
        av[mt][nt] = __builtin_amdgcn_mfma_f32_16x16x32_bf16(af[mt], bfr[nt],
                                                             av[mt][nt], 0, 0, 0);
    __syncthreads();
  }
#pragma unroll
  for (int mt = 0; mt < 4; ++mt) {
    const int m = wave * 64 + mt * 16 + quad * 4;
#pragma unroll
    for (int nt = 0; nt < 4; ++nt) {
      const int pp = nt * 16 + l15;
      *(f4*)(lsm + pp * C_ + m) = av[mt][nt];
    }
  }
  __syncthreads();
  // softmax + nll: wave handles 16 positions, lane covers 4 classes
  const float4 bv = *(const float4*)(outb + lane * 4);
  float wsum = 0.f;
  for (int i = 0; i < 16; ++i) {
    const int pp = wave * 16 + i;
    const f4 lv = *(const f4*)(lsm + pp * C_ + lane * 4);
    const float x0 = lv[0] + bv.x, x1 = lv[1] + bv.y, x2 = lv[2] + bv.z,
                x3 = lv[3] + bv.w;
    float mx = fmaxf(fmaxf(x0, x1), fmaxf(x2, x3));
#pragma unroll
    for (int off = 1; off < 64; off <<= 1) mx = fmaxf(mx, __shfl_xor(mx, off));
    float ss = expf(x0 - mx) + expf(x1 - mx) + expf(x2 - mx) + expf(x3 - mx);
#pragma unroll
    for (int off = 1; off < 64; off <<= 1) ss += __shfl_xor(ss, off);
    if (lane == 0) {
      const int t = tgt[b * S_ + n0 + pp];
      wsum += mx + logf(ss) - (lsm[pp * C_ + t] + outb[t]);
    }
  }
  if (lane == 0) atomicAdd(acc, wsum);
}

__global__ void k_final(const float* __restrict__ acc, float* __restrict__ out) {
  out[0] = acc[0] * (1.0f / 4096.0f);
}

extern "C" void kernel_launch(void* const* d_in, const int* in_sizes, int n_in,
                              void* d_out, int out_size, void* d_ws,
                              size_t ws_size, hipStream_t stream) {
  const int* inp = (const int*)d_in[0];
  const int* tgt = (const int*)d_in[1];
  const float* emb = (const float*)d_in[2];
  const float* w0s = (const float*)d_in[3];
  const float* w1s = (const float*)d_in[4];
  const float* w2s = (const float*)d_in[5];
  const float* out_w = (const float*)d_in[6];
  const float* out_b = (const float*)d_in[7];

  char* ws = (char*)d_ws;
  float* acc = (float*)(ws + 0);
  __bf16* zp = (__bf16*)(ws + 256);
  float* a_st = (float*)(ws + 4096);
  float* b_st = (float*)(ws + 8392704L);
  __bf16* h = (__bf16*)(ws + 16781312L);
  __bf16* Y1 = (__bf16*)(ws + 20975616L);     // [b][s][3I] bf16
  __bf16* Y2 = (__bf16*)(ws + 46141440L);     // [b*3+p][s][I] bf16
  float* Y3 = (float*)(ws + 71307264L);       // [b*3+p][s][F] f32
  __bf16* W1r = (__bf16*)(ws + 96473088L);    // [l][p][i][3I] bf16
  __bf16* streams = (__bf16*)(ws + 134221824L);
  __bf16* W0c = (__bf16*)(ws + 146804736L);   // w0s as bf16
  __bf16* W2c = (__bf16*)(ws + 153096192L);   // w2s as bf16
  __bf16* OWc = (__bf16*)(ws + 159387648L);   // out_w as bf16

  hipMemsetAsync(ws, 0, 4096, stream);  // acc + zero page
  k_prep<<<30976, 256, 0, stream>>>(w0s, w2s, out_w, w1s, W0c, W2c, OWc, W1r);
  k_embed<<<4096, 64, 0, stream>>>(inp, emb, a_st, b_st, h);

  for (int l = 0; l < 2; ++l) {
    // conv1: (3I x F) @ h  -> Y1, relu, bf16
    gemm_bt<1, true, true, 128, 512><<<dim3(16, 24, 2), 256, 0, stream>>>(
        W0c + (long)l * 1572864L, h, Y1, zp, 3072, 512, 1, 0L, 0L, 1048576L,
        6291456L);
    // conv2: causal k=3 (I x 3I) @ Y1 -> Y2, relu, bf16
    gemm_bt<3, true, true, 128, 3072><<<dim3(16, 8, 6), 256, 0, stream>>>(
        W1r + (long)l * 9437184L, Y1, Y2, zp, 1024, 3072, 3, 3145728L, 1024L,
        6291456L, 2097152L);
    // conv3: (F x I) @ Y2 -> Y3, f32; 64-wide n-tiles for 768-block balance
    gemm_bt<1, false, false, 64, 1024><<<dim3(32, 4, 6), 256, 0, stream>>>(
        W2c + (long)l * 1572864L, Y2, Y3, zp, 512, 1024, 3, 524288L, 2097152L,
        6291456L, 1048576L);
    k_cell<<<4096, 64, 0, stream>>>(Y3, a_st, b_st, (l == 0) ? h : streams,
                                    (l == 1) ? 1 : 0);
  }

  k_logits_nll<<<dim3(32, 2), 256, 0, stream>>>(OWc, streams, out_b, tgt, acc);
  k_final<<<1, 1, 0, stream>>>(acc, (float*)d_out);
}

// Round 6
// 387.831 us; speedup vs baseline: 1.9070x; 1.3158x over previous
//
#include <hip/hip_runtime.h>

#define S_ 2048
#define F_ 512
#define I_ 1024
#define C_ 256

typedef float f4 __attribute__((ext_vector_type(4)));
typedef __bf16 bf8 __attribute__((ext_vector_type(8)));
typedef __bf16 bf4 __attribute__((ext_vector_type(4)));
typedef int i4v __attribute__((ext_vector_type(4)));
typedef int i8v __attribute__((ext_vector_type(8)));

__device__ __forceinline__ void gload_lds16(const void* g, void* l) {
  __builtin_amdgcn_global_load_lds(
      (const __attribute__((address_space(1))) void*)g,
      (__attribute__((address_space(3))) void*)l, 16, 0, 0);
}

__device__ __forceinline__ float fe_val(int f) {
  const float PI_F = 3.14159265358979323846f;
  float additive = (f & 1) ? 0.0f : 1.0f;
  float fv = ((float)(f + 1) - additive) * 0.5f;
  fv = fv * (8.0f / (float)F_) - logf((float)C_ / (2.0f * PI_F));
  return expf(fv) + additive * PI_F;
}

// bf16 GEMM (conv1/conv3): C[n][m] = sum_k A[m][k]*B'[k][n], B position-major.
// OUT: 0=f32, 1=bf16, 2=fp8-e4m3. LDS XOR-swizzle slot q^((r>>1)&3).
template <bool RELU, int OUT, int NTILE, int K>
__global__ __launch_bounds__(256) void gemm_bt(
    const __bf16* __restrict__ Ab, const __bf16* __restrict__ Bb,
    void* __restrict__ Cb, int M, int ldb, int PZ, long sAp, long sBp,
    long sBb, long sCz) {
  constexpr int NF = NTILE / 32;
  constexpr int NIT = K / 64;
  const int tid = threadIdx.x;
  const int z = blockIdx.z;
  const int p = z % PZ;
  const int bb = z / PZ;
  const __bf16* A = Ab + (long)p * sAp;
  const __bf16* Bt = Bb + (long)bb * sBb + (long)p * sBp;
  const int m0 = blockIdx.y * 128;
  const int n0 = blockIdx.x * NTILE;
  __shared__ __bf16 As[2][128 * 32];
  __shared__ __bf16 Bs[2][NTILE * 32];
  const int lane = tid & 63;
  const int wave = tid >> 6;
  const int wr = wave >> 1;
  const int wc = wave & 1;
  const int l15 = lane & 15;
  const int quad = lane >> 4;
  f4 acc[4][NF] = {};
  const int cr = tid >> 2;
  const int csw = (((tid & 3) ^ ((cr >> 1) & 3)) << 3);
  const int roff = ((quad ^ ((l15 >> 1) & 3)) << 3);

  const __bf16* pA = A + (long)(m0 + cr) * K + csw;
  const __bf16* pB[NTILE / 64];
#pragma unroll
  for (int i = 0; i < NTILE / 64; ++i)
    pB[i] = Bt + (long)(n0 + i * 64 + cr) * ldb + csw;
#pragma unroll
  for (int it = 0; it < NIT; ++it) {
#pragma unroll
    for (int sub = 0; sub < 2; ++sub) {
#pragma unroll
      for (int i = 0; i < 2; ++i)
        gload_lds16(pA + ((long)i * 64 * K + it * 64 + sub * 32),
                    &As[sub][(i * 256 + wave * 64) * 8]);
#pragma unroll
      for (int i = 0; i < NTILE / 64; ++i)
        gload_lds16(pB[i] + (it * 64 + sub * 32),
                    &Bs[sub][(i * 256 + wave * 64) * 8]);
    }
    __syncthreads();
#pragma unroll
    for (int sub = 0; sub < 2; ++sub) {
      bf8 af[4], bfr[NF];
#pragma unroll
      for (int mt = 0; mt < 4; ++mt)
        af[mt] = *(const bf8*)(&As[sub][(wr * 64 + mt * 16 + l15) * 32 + roff]);
#pragma unroll
      for (int nt = 0; nt < NF; ++nt)
        bfr[nt] = *(const bf8*)(&Bs[sub][(wc * (NTILE / 2) + nt * 16 + l15) * 32 +
                                         roff]);
#pragma unroll
      for (int mt = 0; mt < 4; ++mt)
#pragma unroll
        for (int nt = 0; nt < NF; ++nt)
          acc[mt][nt] = __builtin_amdgcn_mfma_f32_16x16x32_bf16(
              af[mt], bfr[nt], acc[mt][nt], 0, 0, 0);
    }
    __syncthreads();
  }
#pragma unroll
  for (int mt = 0; mt < 4; ++mt) {
    const int m = m0 + wr * 64 + mt * 16 + quad * 4;
#pragma unroll
    for (int nt = 0; nt < NF; ++nt) {
      const int n = n0 + wc * (NTILE / 2) + nt * 16 + l15;
      f4 v = acc[mt][nt];
      if (RELU) {
#pragma unroll
        for (int q = 0; q < 4; ++q) v[q] = fmaxf(v[q], 0.0f);
      }
      if (OUT == 1) {
        bf4 o;
#pragma unroll
        for (int q = 0; q < 4; ++q) o[q] = (__bf16)v[q];
        *(bf4*)((__bf16*)Cb + (long)z * sCz + (long)n * M + m) = o;
      } else if (OUT == 2) {
        int r = __builtin_amdgcn_cvt_pk_fp8_f32(v[0], v[1], 0, false);
        r = __builtin_amdgcn_cvt_pk_fp8_f32(v[2], v[3], r, true);
        *(int*)((unsigned char*)Cb + (long)z * sCz + (long)n * M + m) = r;
      } else {
        *(f4*)((float*)Cb + (long)z * sCz + (long)n * M + m) = v;
      }
    }
  }
}

// conv2 in MX-scaled fp8 (K=128 MFMA, scales=1.0; weights pre-scaled x64).
// A: W1f8 [p][1024 rows][3072 k-bytes], B: Y1f8 [b][2048][3072] (p-offset 1024).
// causal: B row (n + t - 2), zero page if negative. Output Y2 bf16 n-major.
__global__ __launch_bounds__(256) void gemm_f8c2(
    const unsigned char* __restrict__ Af8, const unsigned char* __restrict__ Bf8,
    __bf16* __restrict__ Cb, const unsigned char* __restrict__ zpage) {
  __shared__ unsigned char Asm[128 * 128];
  __shared__ unsigned char Bsm[128 * 128];
  const int tid = threadIdx.x;
  const int z = blockIdx.z;
  const int p = z % 3;
  const int b = z / 3;
  const int m0 = blockIdx.y * 128;
  const int n0 = blockIdx.x * 128;
  const unsigned char* A = Af8 + (long)p * 3145728L;
  const unsigned char* B = Bf8 + (long)b * 6291456L + p * 1024;
  const int lane = tid & 63;
  const int wave = tid >> 6;
  const int wr = wave >> 1;
  const int wc = wave & 1;
  const int l15 = lane & 15;
  const int quad = lane >> 4;
  const int cr = tid >> 3;                          // row within 32-row pass
  const int csw = (((tid & 7) ^ (cr & 7)) << 4);    // swizzled 16B chunk
  const int off0 = (((2 * quad) ^ (l15 & 7)) << 4);
  const int off1 = (((2 * quad + 1) ^ (l15 & 7)) << 4);
  f4 acc[4][4] = {};

  for (int t = 0; t < 3; ++t) {
#pragma unroll 1
    for (int it = 0; it < 8; ++it) {
      const int kb = t * 1024 + it * 128;
#pragma unroll
      for (int pass = 0; pass < 4; ++pass) {
        gload_lds16(A + (long)(m0 + pass * 32 + cr) * 3072 + kb + csw,
                    Asm + (pass * 256 + wave * 64) * 16);
        const int rg = n0 + pass * 32 + cr + t - 2;
        const unsigned char* gb = (rg < 0)
                                      ? (zpage + it * 128 + csw)
                                      : (B + (long)rg * 3072 + it * 128 + csw);
        gload_lds16(gb, Bsm + (pass * 256 + wave * 64) * 16);
      }
      __syncthreads();
      i8v af[4], bfr[4];
#pragma unroll
      for (int mt = 0; mt < 4; ++mt) {
        const unsigned char* rp = Asm + (wr * 64 + mt * 16 + l15) * 128;
        const i4v lo = *(const i4v*)(rp + off0);
        const i4v hi = *(const i4v*)(rp + off1);
        af[mt][0] = lo[0]; af[mt][1] = lo[1]; af[mt][2] = lo[2]; af[mt][3] = lo[3];
        af[mt][4] = hi[0]; af[mt][5] = hi[1]; af[mt][6] = hi[2]; af[mt][7] = hi[3];
      }
#pragma unroll
      for (int nt = 0; nt < 4; ++nt) {
        const unsigned char* rp = Bsm + (wc * 64 + nt * 16 + l15) * 128;
        const i4v lo = *(const i4v*)(rp + off0);
        const i4v hi = *(const i4v*)(rp + off1);
        bfr[nt][0] = lo[0]; bfr[nt][1] = lo[1]; bfr[nt][2] = lo[2]; bfr[nt][3] = lo[3];
        bfr[nt][4] = hi[0]; bfr[nt][5] = hi[1]; bfr[nt][6] = hi[2]; bfr[nt][7] = hi[3];
      }
#pragma unroll
      for (int mt = 0; mt < 4; ++mt)
#pragma unroll
        for (int nt = 0; nt < 4; ++nt)
          acc[mt][nt] = __builtin_amdgcn_mfma_scale_f32_16x16x128_f8f6f4(
              af[mt], bfr[nt], acc[mt][nt], 0, 0, 0, 0x7F7F7F7F, 0, 0x7F7F7F7F);
      __syncthreads();
    }
  }
#pragma unroll
  for (int mt = 0; mt < 4; ++mt) {
    const int m = m0 + wr * 64 + mt * 16 + quad * 4;
#pragma unroll
    for (int nt = 0; nt < 4; ++nt) {
      const int n = n0 + wc * 64 + nt * 16 + l15;
      f4 v = acc[mt][nt];
      bf4 o;
#pragma unroll
      for (int q = 0; q < 4; ++q)
        o[q] = (__bf16)fmaxf(v[q] * 0.015625f, 0.0f);  // undo x64, relu
      *(bf4*)(Cb + (long)z * 2097152L + (long)n * 1024 + m) = o;
    }
  }
}

__device__ __forceinline__ void cvt4(const float* __restrict__ s,
                                     __bf16* __restrict__ d, long T) {
  const long i = T * 4;
  const float4 v = *(const float4*)(s + i);
  bf4 o;
  o[0] = (__bf16)v.x;
  o[1] = (__bf16)v.y;
  o[2] = (__bf16)v.z;
  o[3] = (__bf16)v.w;
  *(bf4*)(d + i) = o;
}

__device__ __forceinline__ unsigned char to_fp8(float v) {
  return (unsigned char)(__builtin_amdgcn_cvt_pk_fp8_f32(v, 0.0f, 0, false) &
                         0xFF);
}

// One dispatch: w0s/w2s/out_w f32->bf16, w1s reorder -> fp8 x64.
__global__ void k_prep(const float* __restrict__ w0, const float* __restrict__ w2,
                       const float* __restrict__ ow, const float* __restrict__ w1,
                       __bf16* __restrict__ W0c, __bf16* __restrict__ W2c,
                       __bf16* __restrict__ OWc, unsigned char* __restrict__ W1f8) {
  long T = (long)blockIdx.x * 256 + threadIdx.x;
  if (T < 786432L) {
    cvt4(w0, W0c, T);
    return;
  }
  T -= 786432L;
  if (T < 786432L) {
    cvt4(w2, W2c, T);
    return;
  }
  T -= 786432L;
  if (T < 65536L) {
    cvt4(ow, OWc, T);
    return;
  }
  T -= 65536L;
  // w1s (L,3,I,I,K=3) -> W1f8[(l*3+p)*I+i][t*1024 + j], value x64
  const long j = T & (I_ - 1);
  const long r3 = T >> 10;
  const float* src = w1 + T * 3;
  unsigned char* dst = W1f8 + r3 * 3072 + j;
  dst[0] = to_fp8(src[0] * 64.0f);
  dst[1024] = to_fp8(src[1] * 64.0f);
  dst[2048] = to_fp8(src[2] * 64.0f);
}

// One wave per (b,s): gather embedding -> a/b state (f32) + layer-0 h (bf16).
__global__ __launch_bounds__(64) void k_embed(const int* __restrict__ inp,
                                              const float* __restrict__ emb,
                                              float* __restrict__ a_st,
                                              float* __restrict__ b_st,
                                              __bf16* __restrict__ h) {
  const int col = blockIdx.x;
  const int lane = threadIdx.x;
  const int f0 = lane * 8;
  const float* e = emb + (long)inp[col] * (2 * F_);
  const float4 a0 = *(const float4*)(e + f0);
  const float4 a1 = *(const float4*)(e + f0 + 4);
  const float4 b0 = *(const float4*)(e + F_ + f0);
  const float4 b1 = *(const float4*)(e + F_ + f0 + 4);
  *(float4*)(a_st + (long)col * F_ + f0) = a0;
  *(float4*)(a_st + (long)col * F_ + f0 + 4) = a1;
  *(float4*)(b_st + (long)col * F_ + f0) = b0;
  *(float4*)(b_st + (long)col * F_ + f0 + 4) = b1;
  const float bb[8] = {b0.x, b0.y, b0.z, b0.w, b1.x, b1.y, b1.z, b1.w};
  bf8 o;
#pragma unroll
  for (int q = 0; q < 8; ++q) o[q] = (__bf16)(bb[q] + fe_val(f0 + q));
  *(bf8*)(h + (long)col * F_ + f0) = o;
}

// One wave per (b,s) column: shfl-scan cumsum, stats, EMA; fuse next h/streams.
__global__ __launch_bounds__(64) void k_cell(const float* __restrict__ Y3,
                                             float* __restrict__ a_st,
                                             float* __restrict__ b_st,
                                             __bf16* __restrict__ outp,
                                             int last) {
  const int col = blockIdx.x;
  const int s = col & (S_ - 1);
  const int b = col >> 11;
  const int lane = threadIdx.x;
  const int f0 = lane * 8;
  const float* d = Y3 + ((long)(3 * b + 0) * S_ + s) * F_ + f0;
  const float* sc = Y3 + ((long)(3 * b + 1) * S_ + s) * F_ + f0;
  const float* sh = Y3 + ((long)(3 * b + 2) * S_ + s) * F_ + f0;
  float* ap = a_st + (long)col * F_ + f0;
  float* bp = b_st + (long)col * F_ + f0;
  const float inv_div = 1.0f / (float)(s + 1);

  const float4 d0 = *(const float4*)d;
  const float4 d1 = *(const float4*)(d + 4);
  const float4 sc0 = *(const float4*)sc;
  const float4 sc1 = *(const float4*)(sc + 4);
  const float4 sh0 = *(const float4*)sh;
  const float4 sh1 = *(const float4*)(sh + 4);

  float c[8];
  c[0] = d0.x;
  c[1] = c[0] + d0.y;
  c[2] = c[1] + d0.z;
  c[3] = c[2] + d0.w;
  c[4] = c[3] + d1.x;
  c[5] = c[4] + d1.y;
  c[6] = c[5] + d1.z;
  c[7] = c[6] + d1.w;
  const float tot = c[7];
  float scan = tot;
#pragma unroll
  for (int off = 1; off < 64; off <<= 1) {
    float nb = __shfl_up(scan, off);
    if (lane >= off) scan += nb;
  }
  const float base = scan - tot;

  float v[8];
  v[0] = (base + c[0]) * inv_div * sc0.x + sh0.x;
  v[1] = (base + c[1]) * inv_div * sc0.y + sh0.y;
  v[2] = (base + c[2]) * inv_div * sc0.z + sh0.z;
  v[3] = (base + c[3]) * inv_div * sc0.w + sh0.w;
  v[4] = (base + c[4]) * inv_div * sc1.x + sh1.x;
  v[5] = (base + c[5]) * inv_div * sc1.y + sh1.y;
  v[6] = (base + c[6]) * inv_div * sc1.z + sh1.z;
  v[7] = (base + c[7]) * inv_div * sc1.w + sh1.w;

  float sum = 0.f, ssq = 0.f;
#pragma unroll
  for (int q = 0; q < 8; ++q) {
    sum += v[q];
    ssq += v[q] * v[q];
  }
#pragma unroll
  for (int off = 1; off < 64; off <<= 1) {
    sum += __shfl_xor(sum, off);
    ssq += __shfl_xor(ssq, off);
  }
  const float mean = sum * (1.0f / (float)F_);
  const float nsq = fmaxf(ssq - (float)F_ * mean * mean, 0.0f);
  const float denom = sqrtf(nsq) * 0.04419417382415922f + 1e-5f;
  const float isc = 0.7071067811865476f / denom;

  const float4 av0 = *(const float4*)ap;
  const float4 av1 = *(const float4*)(ap + 4);
  const float4 bv0 = *(const float4*)bp;
  const float4 bv1 = *(const float4*)(bp + 4);
  float an[8], bn[8];
  const float ai[8] = {av0.x, av0.y, av0.z, av0.w, av1.x, av1.y, av1.z, av1.w};
  const float bi[8] = {bv0.x, bv0.y, bv0.z, bv0.w, bv1.x, bv1.y, bv1.z, bv1.w};
#pragma unroll
  for (int q = 0; q < 8; ++q) {
    const float cell = (v[q] - mean) * isc;
    an[q] = 0.99f * ai[q] + 0.01f * cell;
    bn[q] = bi[q] + an[q];
  }
  *(float4*)ap = {an[0], an[1], an[2], an[3]};
  *(float4*)(ap + 4) = {an[4], an[5], an[6], an[7]};
  *(float4*)bp = {bn[0], bn[1], bn[2], bn[3]};
  *(float4*)(bp + 4) = {bn[4], bn[5], bn[6], bn[7]};
  if (!last) {
    bf8 o;
#pragma unroll
    for (int q = 0; q < 8; ++q) o[q] = (__bf16)(bn[q] + fe_val(f0 + q));
    *(bf8*)(outp + (long)col * F_ + f0) = o;
  } else {
    bf8 oa, ob;
#pragma unroll
    for (int q = 0; q < 8; ++q) {
      oa[q] = (__bf16)an[q];
      ob[q] = (__bf16)bn[q];
    }
    *(bf8*)(outp + (long)col * (2 * F_) + f0) = oa;
    *(bf8*)(outp + (long)col * (2 * F_) + F_ + f0) = ob;
  }
}

// Fused logits GEMM + bias + softmax + NLL.
__global__ __launch_bounds__(256) void k_logits_nll(
    const __bf16* __restrict__ A, const __bf16* __restrict__ Bb,
    const float* __restrict__ outb, const int* __restrict__ tgt,
    float* __restrict__ acc) {
  __shared__ __bf16 As[256 * 32];
  __shared__ __bf16 Bs[64 * 32];
  __shared__ float lsm[64 * 256];
  const int tid = threadIdx.x;
  const int b = blockIdx.y;
  const int n0 = blockIdx.x * 64;
  const __bf16* Bt = Bb + (long)b * (S_ * 2 * F_) + (long)n0 * (2 * F_);
  const int lane = tid & 63;
  const int wave = tid >> 6;
  const int l15 = lane & 15;
  const int quad = lane >> 4;
  const int cr = tid >> 2;
  const int csw = (((tid & 3) ^ ((cr >> 1) & 3)) << 3);
  const int roff = ((quad ^ ((l15 >> 1) & 3)) << 3);
  f4 av[4][4] = {};
  for (int k0 = 0; k0 < 2 * F_; k0 += 32) {
#pragma unroll
    for (int i = 0; i < 4; ++i)
      gload_lds16(A + (long)(i * 64 + cr) * (2 * F_) + (k0 + csw),
                  As + ((i * 256 + (wave << 6)) << 3));
    gload_lds16(Bt + (long)cr * (2 * F_) + (k0 + csw), Bs + ((wave << 6) << 3));
    __syncthreads();
    bf8 af[4], bfr[4];
#pragma unroll
    for (int mt = 0; mt < 4; ++mt)
      af[mt] = *(const bf8*)(As + (wave * 64 + mt * 16 + l15) * 32 + roff);
#pragma unroll
    for (int nt = 0; nt < 4; ++nt)
      bfr[nt] = *(const bf8*)(Bs + (nt * 16 + l15) * 32 + roff);
#pragma unroll
    for (int mt = 0; mt < 4; ++mt)
#pragma unroll
      for (int nt = 0; nt < 4; ++nt)
        av[mt][nt] = __builtin_amdgcn_mfma_f32_16x16x32_bf16(af[mt], bfr[nt],
                                                             av[mt][nt], 0, 0, 0);
    __syncthreads();
  }
#pragma unroll
  for (int mt = 0; mt < 4; ++mt) {
    const int m = wave * 64 + mt * 16 + quad * 4;
#pragma unroll
    for (int nt = 0; nt < 4; ++nt) {
      const int pp = nt * 16 + l15;
      *(f4*)(lsm + pp * C_ + m) = av[mt][nt];
    }
  }
  __syncthreads();
  const float4 bv = *(const float4*)(outb + lane * 4);
  float wsum = 0.f;
  for (int i = 0; i < 16; ++i) {
    const int pp = wave * 16 + i;
    const f4 lv = *(const f4*)(lsm + pp * C_ + lane * 4);
    const float x0 = lv[0] + bv.x, x1 = lv[1] + bv.y, x2 = lv[2] + bv.z,
                x3 = lv[3] + bv.w;
    float mx = fmaxf(fmaxf(x0, x1), fmaxf(x2, x3));
#pragma unroll
    for (int off = 1; off < 64; off <<= 1) mx = fmaxf(mx, __shfl_xor(mx, off));
    float ss = expf(x0 - mx) + expf(x1 - mx) + expf(x2 - mx) + expf(x3 - mx);
#pragma unroll
    for (int off = 1; off < 64; off <<= 1) ss += __shfl_xor(ss, off);
    if (lane == 0) {
      const int t = tgt[b * S_ + n0 + pp];
      wsum += mx + logf(ss) - (lsm[pp * C_ + t] + outb[t]);
    }
  }
  if (lane == 0) atomicAdd(acc, wsum);
}

__global__ void k_final(const float* __restrict__ acc, float* __restrict__ out) {
  out[0] = acc[0] * (1.0f / 4096.0f);
}

extern "C" void kernel_launch(void* const* d_in, const int* in_sizes, int n_in,
                              void* d_out, int out_size, void* d_ws,
                              size_t ws_size, hipStream_t stream) {
  const int* inp = (const int*)d_in[0];
  const int* tgt = (const int*)d_in[1];
  const float* emb = (const float*)d_in[2];
  const float* w0s = (const float*)d_in[3];
  const float* w1s = (const float*)d_in[4];
  const float* w2s = (const float*)d_in[5];
  const float* out_w = (const float*)d_in[6];
  const float* out_b = (const float*)d_in[7];

  char* ws = (char*)d_ws;
  float* acc = (float*)(ws + 0);
  unsigned char* zp = (unsigned char*)(ws + 256);
  float* a_st = (float*)(ws + 4096);
  float* b_st = (float*)(ws + 8392704L);
  __bf16* h = (__bf16*)(ws + 16781312L);
  unsigned char* Y1f8 = (unsigned char*)(ws + 20975616L);  // [b][s][3I] fp8
  __bf16* Y2 = (__bf16*)(ws + 46141440L);                  // [b*3+p][s][I] bf16
  float* Y3 = (float*)(ws + 71307264L);                    // [b*3+p][s][F] f32
  unsigned char* W1f8 = (unsigned char*)(ws + 96473088L);  // [l][p][i][3072] fp8
  __bf16* streams = (__bf16*)(ws + 134221824L);
  __bf16* W0c = (__bf16*)(ws + 146804736L);
  __bf16* W2c = (__bf16*)(ws + 153096192L);
  __bf16* OWc = (__bf16*)(ws + 159387648L);

  hipMemsetAsync(ws, 0, 4096, stream);  // acc + zero page
  k_prep<<<30976, 256, 0, stream>>>(w0s, w2s, out_w, w1s, W0c, W2c, OWc, W1f8);
  k_embed<<<4096, 64, 0, stream>>>(inp, emb, a_st, b_st, h);

  for (int l = 0; l < 2; ++l) {
    // conv1: (3I x F) @ h -> Y1 fp8, relu
    gemm_bt<true, 2, 128, 512><<<dim3(16, 24, 2), 256, 0, stream>>>(
        W0c + (long)l * 1572864L, h, Y1f8, 3072, 512, 1, 0L, 0L, 1048576L,
        6291456L);
    // conv2: causal k=3, MX-fp8 K=128 MFMA -> Y2 bf16, relu
    gemm_f8c2<<<dim3(16, 8, 6), 256, 0, stream>>>(W1f8 + (long)l * 9437184L,
                                                  Y1f8, Y2, zp);
    // conv3: (F x I) @ Y2 -> Y3, f32
    gemm_bt<false, 0, 64, 1024><<<dim3(32, 4, 6), 256, 0, stream>>>(
        W2c + (long)l * 1572864L, Y2, Y3, 512, 1024, 3, 524288L, 2097152L,
        6291456L, 1048576L);
    k_cell<<<4096, 64, 0, stream>>>(Y3, a_st, b_st, (l == 0) ? h : streams,
                                    (l == 1) ? 1 : 0);
  }

  k_logits_nll<<<dim3(32, 2), 256, 0, stream>>>(OWc, streams, out_b, tgt, acc);
  k_final<<<1, 1, 0, stream>>>(acc, (float*)d_out);
}

// Round 7
// 367.985 us; speedup vs baseline: 2.0099x; 1.0539x over previous
//
#include <hip/hip_runtime.h>

#define S_ 2048
#define F_ 512
#define I_ 1024
#define C_ 256

typedef float f4 __attribute__((ext_vector_type(4)));
typedef __bf16 bf8 __attribute__((ext_vector_type(8)));
typedef __bf16 bf4 __attribute__((ext_vector_type(4)));
typedef int i4v __attribute__((ext_vector_type(4)));
typedef int i8v __attribute__((ext_vector_type(8)));
typedef unsigned char u8;

__device__ __forceinline__ void gload_lds16(const void* g, void* l) {
  __builtin_amdgcn_global_load_lds(
      (const __attribute__((address_space(1))) void*)g,
      (__attribute__((address_space(3))) void*)l, 16, 0, 0);
}

__device__ __forceinline__ float fe_val(int f) {
  const float PI_F = 3.14159265358979323846f;
  float additive = (f & 1) ? 0.0f : 1.0f;
  float fv = ((float)(f + 1) - additive) * 0.5f;
  fv = fv * (8.0f / (float)F_) - logf((float)C_ / (2.0f * PI_F));
  return expf(fv) + additive * PI_F;
}

// MX-fp8 GEMM: C[n][m] = (1/64)*sum_k A[m][k]*B'[k][n]; weights pre-scaled x64.
// KW=3 causal: k = t*KD + j, B row (n + t - 2), zero page if < 0.
// LDS: per tile-row the 128 k-bytes split into lo (chunks 0-3) / hi (4-7)
// regions of 64-B rows, slot s of row r holds chunk s ^ ((r>>1)&3) --
// reproduces the measured-conflict-free bf16 bank pattern.
// OUT: 0 = f32, 2 = fp8-e4m3. Output n-major (ldc = M).
template <int KW, bool RELU, int OUT, int NTILE, int KD, int LDB>
__global__ __launch_bounds__(256) void gemm_f8(
    const u8* __restrict__ Ab, const u8* __restrict__ Bb, void* __restrict__ Cb,
    const u8* __restrict__ zpage, int M, int PZ, long sAp, long sBp, long sBb,
    long sCz) {
  constexpr int NF = NTILE / 32;  // n-frags per wave
  constexpr int NIT = KD / 128;   // 128-byte k-steps per segment
  constexpr int AK = KW * KD;     // A row stride
  constexpr int BG = NTILE / 32;  // B staging groups (4 KB each)
  __shared__ u8 Asm[16384];
  __shared__ u8 Bsm[NTILE * 128];
  const int tid = threadIdx.x;
  const int z = blockIdx.z;
  const int p = z % PZ;
  const int bb = z / PZ;
  const u8* A = Ab + (long)p * sAp;
  const u8* B = Bb + (long)bb * sBb + (long)p * sBp;
  const int m0 = blockIdx.y * 128;
  const int n0 = blockIdx.x * NTILE;
  const int lane = tid & 63;
  const int wave = tid >> 6;
  const int wr = wave >> 1;
  const int wc = wave & 1;
  const int l15 = lane & 15;
  const int quad = lane >> 4;
  // staging constants: thread covers (row srow-in-group, slot sslot)
  const int srow = tid >> 2;
  const int sslot = tid & 3;
  const int sswz = sslot ^ ((srow >> 1) & 3);  // chunk-in-half fetched
  // read constants
  const int rsw = (l15 >> 1) & 3;
  const int s0 = ((quad & 1) << 1) ^ rsw;      // slot of chunk 2q (in-half)
  const int hbA = (quad >> 1) * 8192;          // lo/hi region base (A)
  const int hbB = (quad >> 1) * (NTILE * 64);  // lo/hi region base (B)
  f4 acc[4][NF] = {};

  const u8* pA[4];
#pragma unroll
  for (int g = 0; g < 4; ++g) {
    const int row = (g & 1) * 64 + srow;
    const int chunk = (g >> 1) * 4 + sswz;
    pA[g] = A + (long)(m0 + row) * AK + chunk * 16;
  }

  for (int t = 0; t < KW; ++t) {
    const u8* pB[BG];
#pragma unroll
    for (int g = 0; g < BG; ++g) {
      const int row = (BG == 4 ? (g & 1) * 64 : 0) + srow;
      const int chunk = (BG == 4 ? (g >> 1) : g) * 4 + sswz;
      const int rg = n0 + row + ((KW == 3) ? (t - 2) : 0);
      pB[g] = (KW == 3 && rg < 0) ? (zpage + chunk * 16)
                                  : (B + (long)rg * LDB + chunk * 16);
    }
    const long ka = (long)t * KD;
#pragma unroll 1
    for (int it = 0; it < NIT; ++it) {
      const int kb = it * 128;
#pragma unroll
      for (int g = 0; g < 4; ++g)
        gload_lds16(pA[g] + ka + kb, Asm + g * 4096 + wave * 1024);
#pragma unroll
      for (int g = 0; g < BG; ++g)
        gload_lds16(pB[g] + kb, Bsm + g * 4096 + wave * 1024);
      __syncthreads();
      i8v af[4], bfr[NF];
#pragma unroll
      for (int mt = 0; mt < 4; ++mt) {
        const u8* rp = Asm + hbA + (wr * 64 + mt * 16 + l15) * 64;
        const i4v lo = *(const i4v*)(rp + s0 * 16);
        const i4v hi = *(const i4v*)(rp + (s0 ^ 1) * 16);
        af[mt][0] = lo[0]; af[mt][1] = lo[1]; af[mt][2] = lo[2]; af[mt][3] = lo[3];
        af[mt][4] = hi[0]; af[mt][5] = hi[1]; af[mt][6] = hi[2]; af[mt][7] = hi[3];
      }
#pragma unroll
      for (int nt = 0; nt < NF; ++nt) {
        const u8* rp = Bsm + hbB + (wc * (NTILE / 2) + nt * 16 + l15) * 64;
        const i4v lo = *(const i4v*)(rp + s0 * 16);
        const i4v hi = *(const i4v*)(rp + (s0 ^ 1) * 16);
        bfr[nt][0] = lo[0]; bfr[nt][1] = lo[1]; bfr[nt][2] = lo[2]; bfr[nt][3] = lo[3];
        bfr[nt][4] = hi[0]; bfr[nt][5] = hi[1]; bfr[nt][6] = hi[2]; bfr[nt][7] = hi[3];
      }
#pragma unroll
      for (int mt = 0; mt < 4; ++mt)
#pragma unroll
        for (int nt = 0; nt < NF; ++nt)
          acc[mt][nt] = __builtin_amdgcn_mfma_scale_f32_16x16x128_f8f6f4(
              af[mt], bfr[nt], acc[mt][nt], 0, 0, 0, 0x7F7F7F7F, 0, 0x7F7F7F7F);
      __syncthreads();
    }
  }
#pragma unroll
  for (int mt = 0; mt < 4; ++mt) {
    const int m = m0 + wr * 64 + mt * 16 + quad * 4;
#pragma unroll
    for (int nt = 0; nt < NF; ++nt) {
      const int n = n0 + wc * (NTILE / 2) + nt * 16 + l15;
      f4 v = acc[mt][nt];
#pragma unroll
      for (int q = 0; q < 4; ++q) {
        v[q] *= 0.015625f;  // undo weight x64
        if (RELU) v[q] = fmaxf(v[q], 0.0f);
      }
      if (OUT == 2) {
        int r = __builtin_amdgcn_cvt_pk_fp8_f32(v[0], v[1], 0, false);
        r = __builtin_amdgcn_cvt_pk_fp8_f32(v[2], v[3], r, true);
        *(int*)((u8*)Cb + (long)z * sCz + (long)n * M + m) = r;
      } else {
        *(f4*)((float*)Cb + (long)z * sCz + (long)n * M + m) = v;
      }
    }
  }
}

__device__ __forceinline__ void cvt4(const float* __restrict__ s,
                                     __bf16* __restrict__ d, long T) {
  const long i = T * 4;
  const float4 v = *(const float4*)(s + i);
  bf4 o;
  o[0] = (__bf16)v.x;
  o[1] = (__bf16)v.y;
  o[2] = (__bf16)v.z;
  o[3] = (__bf16)v.w;
  *(bf4*)(d + i) = o;
}

__device__ __forceinline__ void cvt4f8(const float* __restrict__ s,
                                       u8* __restrict__ d, long T) {
  const long i = T * 4;
  const float4 v = *(const float4*)(s + i);
  int r = __builtin_amdgcn_cvt_pk_fp8_f32(v.x * 64.0f, v.y * 64.0f, 0, false);
  r = __builtin_amdgcn_cvt_pk_fp8_f32(v.z * 64.0f, v.w * 64.0f, r, true);
  *(int*)(d + i) = r;
}

__device__ __forceinline__ u8 to_fp8(float v) {
  return (u8)(__builtin_amdgcn_cvt_pk_fp8_f32(v, 0.0f, 0, false) & 0xFF);
}

// One dispatch: w0s/w2s -> fp8 x64, out_w -> bf16, w1s reorder -> fp8 x64.
__global__ void k_prep(const float* __restrict__ w0, const float* __restrict__ w2,
                       const float* __restrict__ ow, const float* __restrict__ w1,
                       u8* __restrict__ W0f8, u8* __restrict__ W2f8,
                       __bf16* __restrict__ OWc, u8* __restrict__ W1f8) {
  long T = (long)blockIdx.x * 256 + threadIdx.x;
  if (T < 786432L) {
    cvt4f8(w0, W0f8, T);
    return;
  }
  T -= 786432L;
  if (T < 786432L) {
    cvt4f8(w2, W2f8, T);
    return;
  }
  T -= 786432L;
  if (T < 65536L) {
    cvt4(ow, OWc, T);
    return;
  }
  T -= 65536L;
  // w1s (L,3,I,I,K=3) -> W1f8[(l*3+p)*I+i][t*1024 + j], value x64
  const long j = T & (I_ - 1);
  const long r3 = T >> 10;
  const float* src = w1 + T * 3;
  u8* dst = W1f8 + r3 * 3072 + j;
  dst[0] = to_fp8(src[0] * 64.0f);
  dst[1024] = to_fp8(src[1] * 64.0f);
  dst[2048] = to_fp8(src[2] * 64.0f);
}

// One wave per (b,s): gather embedding -> a/b state (f32) + layer-0 h (fp8).
__global__ __launch_bounds__(64) void k_embed(const int* __restrict__ inp,
                                              const float* __restrict__ emb,
                                              float* __restrict__ a_st,
                                              float* __restrict__ b_st,
                                              u8* __restrict__ h) {
  const int col = blockIdx.x;
  const int lane = threadIdx.x;
  const int f0 = lane * 8;
  const float* e = emb + (long)inp[col] * (2 * F_);
  const float4 a0 = *(const float4*)(e + f0);
  const float4 a1 = *(const float4*)(e + f0 + 4);
  const float4 b0 = *(const float4*)(e + F_ + f0);
  const float4 b1 = *(const float4*)(e + F_ + f0 + 4);
  *(float4*)(a_st + (long)col * F_ + f0) = a0;
  *(float4*)(a_st + (long)col * F_ + f0 + 4) = a1;
  *(float4*)(b_st + (long)col * F_ + f0) = b0;
  *(float4*)(b_st + (long)col * F_ + f0 + 4) = b1;
  const float bb[8] = {b0.x, b0.y, b0.z, b0.w, b1.x, b1.y, b1.z, b1.w};
  float hv[8];
#pragma unroll
  for (int q = 0; q < 8; ++q) hv[q] = bb[q] + fe_val(f0 + q);
  int lo = __builtin_amdgcn_cvt_pk_fp8_f32(hv[0], hv[1], 0, false);
  lo = __builtin_amdgcn_cvt_pk_fp8_f32(hv[2], hv[3], lo, true);
  int hi = __builtin_amdgcn_cvt_pk_fp8_f32(hv[4], hv[5], 0, false);
  hi = __builtin_amdgcn_cvt_pk_fp8_f32(hv[6], hv[7], hi, true);
  *(int2*)(h + (long)col * F_ + f0) = {lo, hi};
}

// One wave per (b,s) column: shfl-scan cumsum, stats, EMA; fuse next h (fp8)
// or final streams (bf16).
__global__ __launch_bounds__(64) void k_cell(const float* __restrict__ Y3,
                                             float* __restrict__ a_st,
                                             float* __restrict__ b_st,
                                             void* __restrict__ outp,
                                             int last) {
  const int col = blockIdx.x;
  const int s = col & (S_ - 1);
  const int b = col >> 11;
  const int lane = threadIdx.x;
  const int f0 = lane * 8;
  const float* d = Y3 + ((long)(3 * b + 0) * S_ + s) * F_ + f0;
  const float* sc = Y3 + ((long)(3 * b + 1) * S_ + s) * F_ + f0;
  const float* sh = Y3 + ((long)(3 * b + 2) * S_ + s) * F_ + f0;
  float* ap = a_st + (long)col * F_ + f0;
  float* bp = b_st + (long)col * F_ + f0;
  const float inv_div = 1.0f / (float)(s + 1);

  const float4 d0 = *(const float4*)d;
  const float4 d1 = *(const float4*)(d + 4);
  const float4 sc0 = *(const float4*)sc;
  const float4 sc1 = *(const float4*)(sc + 4);
  const float4 sh0 = *(const float4*)sh;
  const float4 sh1 = *(const float4*)(sh + 4);

  float c[8];
  c[0] = d0.x;
  c[1] = c[0] + d0.y;
  c[2] = c[1] + d0.z;
  c[3] = c[2] + d0.w;
  c[4] = c[3] + d1.x;
  c[5] = c[4] + d1.y;
  c[6] = c[5] + d1.z;
  c[7] = c[6] + d1.w;
  const float tot = c[7];
  float scan = tot;
#pragma unroll
  for (int off = 1; off < 64; off <<= 1) {
    float nb = __shfl_up(scan, off);
    if (lane >= off) scan += nb;
  }
  const float base = scan - tot;

  float v[8];
  v[0] = (base + c[0]) * inv_div * sc0.x + sh0.x;
  v[1] = (base + c[1]) * inv_div * sc0.y + sh0.y;
  v[2] = (base + c[2]) * inv_div * sc0.z + sh0.z;
  v[3] = (base + c[3]) * inv_div * sc0.w + sh0.w;
  v[4] = (base + c[4]) * inv_div * sc1.x + sh1.x;
  v[5] = (base + c[5]) * inv_div * sc1.y + sh1.y;
  v[6] = (base + c[6]) * inv_div * sc1.z + sh1.z;
  v[7] = (base + c[7]) * inv_div * sc1.w + sh1.w;

  float sum = 0.f, ssq = 0.f;
#pragma unroll
  for (int q = 0; q < 8; ++q) {
    sum += v[q];
    ssq += v[q] * v[q];
  }
#pragma unroll
  for (int off = 1; off < 64; off <<= 1) {
    sum += __shfl_xor(sum, off);
    ssq += __shfl_xor(ssq, off);
  }
  const float mean = sum * (1.0f / (float)F_);
  const float nsq = fmaxf(ssq - (float)F_ * mean * mean, 0.0f);
  const float denom = sqrtf(nsq) * 0.04419417382415922f + 1e-5f;
  const float isc = 0.7071067811865476f / denom;

  const float4 av0 = *(const float4*)ap;
  const float4 av1 = *(const float4*)(ap + 4);
  const float4 bv0 = *(const float4*)bp;
  const float4 bv1 = *(const float4*)(bp + 4);
  float an[8], bn[8];
  const float ai[8] = {av0.x, av0.y, av0.z, av0.w, av1.x, av1.y, av1.z, av1.w};
  const float bi[8] = {bv0.x, bv0.y, bv0.z, bv0.w, bv1.x, bv1.y, bv1.z, bv1.w};
#pragma unroll
  for (int q = 0; q < 8; ++q) {
    const float cell = (v[q] - mean) * isc;
    an[q] = 0.99f * ai[q] + 0.01f * cell;
    bn[q] = bi[q] + an[q];
  }
  *(float4*)ap = {an[0], an[1], an[2], an[3]};
  *(float4*)(ap + 4) = {an[4], an[5], an[6], an[7]};
  *(float4*)bp = {bn[0], bn[1], bn[2], bn[3]};
  *(float4*)(bp + 4) = {bn[4], bn[5], bn[6], bn[7]};
  if (!last) {
    float hv[8];
#pragma unroll
    for (int q = 0; q < 8; ++q) hv[q] = bn[q] + fe_val(f0 + q);
    int lo = __builtin_amdgcn_cvt_pk_fp8_f32(hv[0], hv[1], 0, false);
    lo = __builtin_amdgcn_cvt_pk_fp8_f32(hv[2], hv[3], lo, true);
    int hi = __builtin_amdgcn_cvt_pk_fp8_f32(hv[4], hv[5], 0, false);
    hi = __builtin_amdgcn_cvt_pk_fp8_f32(hv[6], hv[7], hi, true);
    *(int2*)((u8*)outp + (long)col * F_ + f0) = {lo, hi};
  } else {
    bf8 oa, ob;
#pragma unroll
    for (int q = 0; q < 8; ++q) {
      oa[q] = (__bf16)an[q];
      ob[q] = (__bf16)bn[q];
    }
    *(bf8*)((__bf16*)outp + (long)col * (2 * F_) + f0) = oa;
    *(bf8*)((__bf16*)outp + (long)col * (2 * F_) + F_ + f0) = ob;
  }
}

// Fused logits GEMM (bf16) + bias + softmax + NLL.
__global__ __launch_bounds__(256) void k_logits_nll(
    const __bf16* __restrict__ A, const __bf16* __restrict__ Bb,
    const float* __restrict__ outb, const int* __restrict__ tgt,
    float* __restrict__ acc) {
  __shared__ __bf16 As[256 * 32];
  __shared__ __bf16 Bs[64 * 32];
  __shared__ float lsm[64 * 256];
  const int tid = threadIdx.x;
  const int b = blockIdx.y;
  const int n0 = blockIdx.x * 64;
  const __bf16* Bt = Bb + (long)b * (S_ * 2 * F_) + (long)n0 * (2 * F_);
  const int lane = tid & 63;
  const int wave = tid >> 6;
  const int l15 = lane & 15;
  const int quad = lane >> 4;
  const int cr = tid >> 2;
  const int csw = (((tid & 3) ^ ((cr >> 1) & 3)) << 3);
  const int roff = ((quad ^ ((l15 >> 1) & 3)) << 3);
  f4 av[4][4] = {};
  for (int k0 = 0; k0 < 2 * F_; k0 += 32) {
#pragma unroll
    for (int i = 0; i < 4; ++i)
      gload_lds16(A + (long)(i * 64 + cr) * (2 * F_) + (k0 + csw),
                  As + ((i * 256 + (wave << 6)) << 3));
    gload_lds16(Bt + (long)cr * (2 * F_) + (k0 + csw), Bs + ((wave << 6) << 3));
    __syncthreads();
    bf8 af[4], bfr[4];
#pragma unroll
    for (int mt = 0; mt < 4; ++mt)
      af[mt] = *(const bf8*)(As + (wave * 64 + mt * 16 + l15) * 32 + roff);
#pragma unroll
    for (int nt = 0; nt < 4; ++nt)
      bfr[nt] = *(const bf8*)(Bs + (nt * 16 + l15) * 32 + roff);
#pragma unroll
    for (int mt = 0; mt < 4; ++mt)
#pragma unroll
      for (int nt = 0; nt < 4; ++nt)
        av[mt][nt] = __builtin_amdgcn_mfma_f32_16x16x32_bf16(af[mt], bfr[nt],
                                                             av[mt][nt], 0, 0, 0);
    __syncthreads();
  }
#pragma unroll
  for (int mt = 0; mt < 4; ++mt) {
    const int m = wave * 64 + mt * 16 + quad * 4;
#pragma unroll
    for (int nt = 0; nt < 4; ++nt) {
      const int pp = nt * 16 + l15;
      *(f4*)(lsm + pp * C_ + m) = av[mt][nt];
    }
  }
  __syncthreads();
  const float4 bv = *(const float4*)(outb + lane * 4);
  float wsum = 0.f;
  for (int i = 0; i < 16; ++i) {
    const int pp = wave * 16 + i;
    const f4 lv = *(const f4*)(lsm + pp * C_ + lane * 4);
    const float x0 = lv[0] + bv.x, x1 = lv[1] + bv.y, x2 = lv[2] + bv.z,
                x3 = lv[3] + bv.w;
    float mx = fmaxf(fmaxf(x0, x1), fmaxf(x2, x3));
#pragma unroll
    for (int off = 1; off < 64; off <<= 1) mx = fmaxf(mx, __shfl_xor(mx, off));
    float ss = expf(x0 - mx) + expf(x1 - mx) + expf(x2 - mx) + expf(x3 - mx);
#pragma unroll
    for (int off = 1; off < 64; off <<= 1) ss += __shfl_xor(ss, off);
    if (lane == 0) {
      const int t = tgt[b * S_ + n0 + pp];
      wsum += mx + logf(ss) - (lsm[pp * C_ + t] + outb[t]);
    }
  }
  if (lane == 0) atomicAdd(acc, wsum);
}

__global__ void k_final(const float* __restrict__ acc, float* __restrict__ out) {
  out[0] = acc[0] * (1.0f / 4096.0f);
}

extern "C" void kernel_launch(void* const* d_in, const int* in_sizes, int n_in,
                              void* d_out, int out_size, void* d_ws,
                              size_t ws_size, hipStream_t stream) {
  const int* inp = (const int*)d_in[0];
  const int* tgt = (const int*)d_in[1];
  const float* emb = (const float*)d_in[2];
  const float* w0s = (const float*)d_in[3];
  const float* w1s = (const float*)d_in[4];
  const float* w2s = (const float*)d_in[5];
  const float* out_w = (const float*)d_in[6];
  const float* out_b = (const float*)d_in[7];

  char* ws = (char*)d_ws;
  float* acc = (float*)(ws + 0);
  u8* zp = (u8*)(ws + 256);
  float* a_st = (float*)(ws + 4096);
  float* b_st = (float*)(ws + 8392704L);
  u8* h = (u8*)(ws + 16781312L);            // [b*2048+s][512] fp8
  u8* Y1f8 = (u8*)(ws + 20975616L);         // [b][s][3072] fp8
  u8* Y2f8 = (u8*)(ws + 46141440L);         // [b*3+p][s][1024] fp8
  float* Y3 = (float*)(ws + 71307264L);     // [b*3+p][s][512] f32
  u8* W1f8 = (u8*)(ws + 96473088L);         // [(l*3+p)*I+i][3072] fp8 x64
  __bf16* streams = (__bf16*)(ws + 134221824L);
  u8* W0f8 = (u8*)(ws + 146804736L);        // [l][3072][512] fp8 x64
  u8* W2f8 = (u8*)(ws + 153096192L);        // [l][3*512][1024] fp8 x64
  __bf16* OWc = (__bf16*)(ws + 159387648L);

  hipMemsetAsync(ws, 0, 4096, stream);  // acc + zero page
  k_prep<<<30976, 256, 0, stream>>>(w0s, w2s, out_w, w1s, W0f8, W2f8, OWc, W1f8);
  k_embed<<<4096, 64, 0, stream>>>(inp, emb, a_st, b_st, h);

  for (int l = 0; l < 2; ++l) {
    // conv1: (3I x F) @ h -> Y1 fp8, relu
    gemm_f8<1, true, 2, 128, 512, 512><<<dim3(16, 24, 2), 256, 0, stream>>>(
        W0f8 + (long)l * 1572864L, h, Y1f8, zp, 3072, 1, 0L, 0L, 1048576L,
        6291456L);
    // conv2: causal k=3 (I x 3I) -> Y2 fp8, relu
    gemm_f8<3, true, 2, 128, 1024, 3072><<<dim3(16, 8, 6), 256, 0, stream>>>(
        W1f8 + (long)l * 9437184L, Y1f8, Y2f8, zp, 1024, 3, 3145728L, 1024L,
        6291456L, 2097152L);
    // conv3: (F x I) @ Y2 -> Y3 f32
    gemm_f8<1, false, 0, 64, 1024, 1024><<<dim3(32, 4, 6), 256, 0, stream>>>(
        W2f8 + (long)l * 1572864L, Y2f8, Y3, zp, 512, 3, 524288L, 2097152L,
        6291456L, 1048576L);
    k_cell<<<4096, 64, 0, stream>>>(Y3, a_st, b_st,
                                    (l == 0) ? (void*)h : (void*)streams,
                                    (l == 1) ? 1 : 0);
  }

  k_logits_nll<<<dim3(32, 2), 256, 0, stream>>>(OWc, streams, out_b, tgt, acc);
  k_final<<<1, 1, 0, stream>>>(acc, (float*)d_out);
}

// Round 8
// 349.682 us; speedup vs baseline: 2.1151x; 1.0523x over previous
//
#include <hip/hip_runtime.h>

#define S_ 2048
#define F_ 512
#define I_ 1024
#define C_ 256

typedef float f4 __attribute__((ext_vector_type(4)));
typedef __bf16 bf8 __attribute__((ext_vector_type(8)));
typedef __bf16 bf4 __attribute__((ext_vector_type(4)));
typedef int i4v __attribute__((ext_vector_type(4)));
typedef int i8v __attribute__((ext_vector_type(8)));
typedef unsigned char u8;

__device__ __forceinline__ void gload_lds16(const void* g, void* l) {
  __builtin_amdgcn_global_load_lds(
      (const __attribute__((address_space(1))) void*)g,
      (__attribute__((address_space(3))) void*)l, 16, 0, 0);
}

__device__ __forceinline__ float fe_val(int f) {
  const float PI_F = 3.14159265358979323846f;
  float additive = (f & 1) ? 0.0f : 1.0f;
  float fv = ((float)(f + 1) - additive) * 0.5f;
  fv = fv * (8.0f / (float)F_) - logf((float)C_ / (2.0f * PI_F));
  return expf(fv) + additive * PI_F;
}

// MX-fp8 GEMM, R6-measured LDS layout: 128-B rows, 16-B chunk slot s of row r
// holds chunk s ^ (r&7). C[n][m] = (1/64)*sum_k A[m][k]*B'[k][n].
// KW=3 causal: k = t*KD + j, B row (n + t - 2), zero page if < 0.
// OUT: 0 = f32, 2 = fp8-e4m3. Output n-major (ldc = M).
template <int KW, bool RELU, int OUT, int NTILE, int KD, int LDB>
__global__ __launch_bounds__(256) void gemm_f8(
    const u8* __restrict__ Ab, const u8* __restrict__ Bb, void* __restrict__ Cb,
    const u8* __restrict__ zpage, int M, int PZ, long sAp, long sBp, long sBb,
    long sCz) {
  constexpr int NF = NTILE / 32;  // n-frags per wave
  constexpr int NIT = KD / 128;   // 128-byte k-steps per segment
  constexpr int AK = KW * KD;     // A row stride
  constexpr int BP = NTILE / 32;  // B staging passes (32 rows each)
  __shared__ u8 Asm[128 * 128];
  __shared__ u8 Bsm[NTILE * 128];
  const int tid = threadIdx.x;
  const int z = blockIdx.z;
  const int p = z % PZ;
  const int bb = z / PZ;
  const u8* A = Ab + (long)p * sAp;
  const u8* B = Bb + (long)bb * sBb + (long)p * sBp;
  const int m0 = blockIdx.y * 128;
  const int n0 = blockIdx.x * NTILE;
  const int lane = tid & 63;
  const int wave = tid >> 6;
  const int wr = wave >> 1;
  const int wc = wave & 1;
  const int l15 = lane & 15;
  const int quad = lane >> 4;
  const int cr = tid >> 3;                        // staged row within pass
  const int csw = (((tid & 7) ^ (cr & 7)) << 4);  // fetched chunk
  const int off0 = (((2 * quad) ^ (l15 & 7)) << 4);
  const int off1 = (((2 * quad + 1) ^ (l15 & 7)) << 4);
  f4 acc[4][NF] = {};

  for (int t = 0; t < KW; ++t) {
    const u8* pA = A + (long)t * KD;
    const u8* pB[BP];
#pragma unroll
    for (int g = 0; g < BP; ++g) {
      const int rg = n0 + g * 32 + cr + ((KW == 3) ? (t - 2) : 0);
      pB[g] = (KW == 3 && rg < 0) ? (zpage + csw) : (B + (long)rg * LDB + csw);
    }
#pragma unroll 1
    for (int it = 0; it < NIT; ++it) {
      const int kb = it * 128;
#pragma unroll
      for (int g = 0; g < 4; ++g)
        gload_lds16(pA + (long)(m0 + g * 32 + cr) * AK + kb + csw,
                    Asm + g * 4096 + wave * 1024);
#pragma unroll
      for (int g = 0; g < BP; ++g)
        gload_lds16(pB[g] + kb, Bsm + g * 4096 + wave * 1024);
      __syncthreads();
      i8v af[4], bfr[NF];
#pragma unroll
      for (int mt = 0; mt < 4; ++mt) {
        const u8* rp = Asm + (wr * 64 + mt * 16 + l15) * 128;
        const i4v lo = *(const i4v*)(rp + off0);
        const i4v hi = *(const i4v*)(rp + off1);
        af[mt][0] = lo[0]; af[mt][1] = lo[1]; af[mt][2] = lo[2]; af[mt][3] = lo[3];
        af[mt][4] = hi[0]; af[mt][5] = hi[1]; af[mt][6] = hi[2]; af[mt][7] = hi[3];
      }
#pragma unroll
      for (int nt = 0; nt < NF; ++nt) {
        const u8* rp = Bsm + (wc * (NTILE / 2) + nt * 16 + l15) * 128;
        const i4v lo = *(const i4v*)(rp + off0);
        const i4v hi = *(const i4v*)(rp + off1);
        bfr[nt][0] = lo[0]; bfr[nt][1] = lo[1]; bfr[nt][2] = lo[2]; bfr[nt][3] = lo[3];
        bfr[nt][4] = hi[0]; bfr[nt][5] = hi[1]; bfr[nt][6] = hi[2]; bfr[nt][7] = hi[3];
      }
#pragma unroll
      for (int mt = 0; mt < 4; ++mt)
#pragma unroll
        for (int nt = 0; nt < NF; ++nt)
          acc[mt][nt] = __builtin_amdgcn_mfma_scale_f32_16x16x128_f8f6f4(
              af[mt], bfr[nt], acc[mt][nt], 0, 0, 0, 0x7F7F7F7F, 0, 0x7F7F7F7F);
      __syncthreads();
    }
  }
#pragma unroll
  for (int mt = 0; mt < 4; ++mt) {
    const int m = m0 + wr * 64 + mt * 16 + quad * 4;
#pragma unroll
    for (int nt = 0; nt < NF; ++nt) {
      const int n = n0 + wc * (NTILE / 2) + nt * 16 + l15;
      f4 v = acc[mt][nt];
#pragma unroll
      for (int q = 0; q < 4; ++q) {
        v[q] *= 0.015625f;  // undo weight x64
        if (RELU) v[q] = fmaxf(v[q], 0.0f);
      }
      if (OUT == 2) {
        int r = __builtin_amdgcn_cvt_pk_fp8_f32(v[0], v[1], 0, false);
        r = __builtin_amdgcn_cvt_pk_fp8_f32(v[2], v[3], r, true);
        *(int*)((u8*)Cb + (long)z * sCz + (long)n * M + m) = r;
      } else {
        *(f4*)((float*)Cb + (long)z * sCz + (long)n * M + m) = v;
      }
    }
  }
}

__device__ __forceinline__ void cvt4(const float* __restrict__ s,
                                     __bf16* __restrict__ d, long T) {
  const long i = T * 4;
  const float4 v = *(const float4*)(s + i);
  bf4 o;
  o[0] = (__bf16)v.x;
  o[1] = (__bf16)v.y;
  o[2] = (__bf16)v.z;
  o[3] = (__bf16)v.w;
  *(bf4*)(d + i) = o;
}

__device__ __forceinline__ void cvt4f8(const float* __restrict__ s,
                                       u8* __restrict__ d, long T) {
  const long i = T * 4;
  const float4 v = *(const float4*)(s + i);
  int r = __builtin_amdgcn_cvt_pk_fp8_f32(v.x * 64.0f, v.y * 64.0f, 0, false);
  r = __builtin_amdgcn_cvt_pk_fp8_f32(v.z * 64.0f, v.w * 64.0f, r, true);
  *(int*)(d + i) = r;
}

__device__ __forceinline__ int pk4f8(float a, float b, float c, float d) {
  int r = __builtin_amdgcn_cvt_pk_fp8_f32(a, b, 0, false);
  return __builtin_amdgcn_cvt_pk_fp8_f32(c, d, r, true);
}

// One dispatch: w0s/w2s -> fp8 x64, out_w -> bf16, w1s reorder -> fp8 x64.
// w1 path vectorized: thread handles 4 j's (3 float4 reads, 3 int stores).
__global__ void k_prep(const float* __restrict__ w0, const float* __restrict__ w2,
                       const float* __restrict__ ow, const float* __restrict__ w1,
                       u8* __restrict__ W0f8, u8* __restrict__ W2f8,
                       __bf16* __restrict__ OWc, u8* __restrict__ W1f8) {
  long T = (long)blockIdx.x * 256 + threadIdx.x;
  if (T < 786432L) {
    cvt4f8(w0, W0f8, T);
    return;
  }
  T -= 786432L;
  if (T < 786432L) {
    cvt4f8(w2, W2f8, T);
    return;
  }
  T -= 786432L;
  if (T < 65536L) {
    cvt4(ow, OWc, T);
    return;
  }
  T -= 65536L;
  // w1s (L,3,I,I,K=3) -> W1f8[(l*3+p)*I+i][t*1024 + j], value x64
  const long j4 = T & 255;   // group of 4 j's
  const long r3 = T >> 8;
  const float* src = w1 + r3 * 3072 + j4 * 12;
  const float4 v0 = *(const float4*)src;       // j0t0 j0t1 j0t2 j1t0
  const float4 v1 = *(const float4*)(src + 4); // j1t1 j1t2 j2t0 j2t1
  const float4 v2 = *(const float4*)(src + 8); // j2t2 j3t0 j3t1 j3t2
  u8* dst = W1f8 + r3 * 3072 + j4 * 4;
  *(int*)(dst) = pk4f8(v0.x * 64.f, v0.w * 64.f, v1.z * 64.f, v2.y * 64.f);
  *(int*)(dst + 1024) = pk4f8(v0.y * 64.f, v1.x * 64.f, v1.w * 64.f, v2.z * 64.f);
  *(int*)(dst + 2048) = pk4f8(v0.z * 64.f, v1.y * 64.f, v2.x * 64.f, v2.w * 64.f);
}

// One wave per (b,s): gather embedding -> a/b state (f32) + layer-0 h (fp8).
__global__ __launch_bounds__(64) void k_embed(const int* __restrict__ inp,
                                              const float* __restrict__ emb,
                                              float* __restrict__ a_st,
                                              float* __restrict__ b_st,
                                              u8* __restrict__ h) {
  const int col = blockIdx.x;
  const int lane = threadIdx.x;
  const int f0 = lane * 8;
  const float* e = emb + (long)inp[col] * (2 * F_);
  const float4 a0 = *(const float4*)(e + f0);
  const float4 a1 = *(const float4*)(e + f0 + 4);
  const float4 b0 = *(const float4*)(e + F_ + f0);
  const float4 b1 = *(const float4*)(e + F_ + f0 + 4);
  *(float4*)(a_st + (long)col * F_ + f0) = a0;
  *(float4*)(a_st + (long)col * F_ + f0 + 4) = a1;
  *(float4*)(b_st + (long)col * F_ + f0) = b0;
  *(float4*)(b_st + (long)col * F_ + f0 + 4) = b1;
  const float bb[8] = {b0.x, b0.y, b0.z, b0.w, b1.x, b1.y, b1.z, b1.w};
  float hv[8];
#pragma unroll
  for (int q = 0; q < 8; ++q) hv[q] = bb[q] + fe_val(f0 + q);
  const int lo = pk4f8(hv[0], hv[1], hv[2], hv[3]);
  const int hi = pk4f8(hv[4], hv[5], hv[6], hv[7]);
  *(int2*)(h + (long)col * F_ + f0) = {lo, hi};
}

// One wave per (b,s) column: shfl-scan cumsum, stats, EMA; fuse next h (fp8)
// or final streams (bf16).
__global__ __launch_bounds__(64) void k_cell(const float* __restrict__ Y3,
                                             float* __restrict__ a_st,
                                             float* __restrict__ b_st,
                                             void* __restrict__ outp,
                                             int last) {
  const int col = blockIdx.x;
  const int s = col & (S_ - 1);
  const int b = col >> 11;
  const int lane = threadIdx.x;
  const int f0 = lane * 8;
  const float* d = Y3 + ((long)(3 * b + 0) * S_ + s) * F_ + f0;
  const float* sc = Y3 + ((long)(3 * b + 1) * S_ + s) * F_ + f0;
  const float* sh = Y3 + ((long)(3 * b + 2) * S_ + s) * F_ + f0;
  float* ap = a_st + (long)col * F_ + f0;
  float* bp = b_st + (long)col * F_ + f0;
  const float inv_div = 1.0f / (float)(s + 1);

  const float4 d0 = *(const float4*)d;
  const float4 d1 = *(const float4*)(d + 4);
  const float4 sc0 = *(const float4*)sc;
  const float4 sc1 = *(const float4*)(sc + 4);
  const float4 sh0 = *(const float4*)sh;
  const float4 sh1 = *(const float4*)(sh + 4);

  float c[8];
  c[0] = d0.x;
  c[1] = c[0] + d0.y;
  c[2] = c[1] + d0.z;
  c[3] = c[2] + d0.w;
  c[4] = c[3] + d1.x;
  c[5] = c[4] + d1.y;
  c[6] = c[5] + d1.z;
  c[7] = c[6] + d1.w;
  const float tot = c[7];
  float scan = tot;
#pragma unroll
  for (int off = 1; off < 64; off <<= 1) {
    float nb = __shfl_up(scan, off);
    if (lane >= off) scan += nb;
  }
  const float base = scan - tot;

  float v[8];
  v[0] = (base + c[0]) * inv_div * sc0.x + sh0.x;
  v[1] = (base + c[1]) * inv_div * sc0.y + sh0.y;
  v[2] = (base + c[2]) * inv_div * sc0.z + sh0.z;
  v[3] = (base + c[3]) * inv_div * sc0.w + sh0.w;
  v[4] = (base + c[4]) * inv_div * sc1.x + sh1.x;
  v[5] = (base + c[5]) * inv_div * sc1.y + sh1.y;
  v[6] = (base + c[6]) * inv_div * sc1.z + sh1.z;
  v[7] = (base + c[7]) * inv_div * sc1.w + sh1.w;

  float sum = 0.f, ssq = 0.f;
#pragma unroll
  for (int q = 0; q < 8; ++q) {
    sum += v[q];
    ssq += v[q] * v[q];
  }
#pragma unroll
  for (int off = 1; off < 64; off <<= 1) {
    sum += __shfl_xor(sum, off);
    ssq += __shfl_xor(ssq, off);
  }
  const float mean = sum * (1.0f / (float)F_);
  const float nsq = fmaxf(ssq - (float)F_ * mean * mean, 0.0f);
  const float denom = sqrtf(nsq) * 0.04419417382415922f + 1e-5f;
  const float isc = 0.7071067811865476f / denom;

  const float4 av0 = *(const float4*)ap;
  const float4 av1 = *(const float4*)(ap + 4);
  const float4 bv0 = *(const float4*)bp;
  const float4 bv1 = *(const float4*)(bp + 4);
  float an[8], bn[8];
  const float ai[8] = {av0.x, av0.y, av0.z, av0.w, av1.x, av1.y, av1.z, av1.w};
  const float bi[8] = {bv0.x, bv0.y, bv0.z, bv0.w, bv1.x, bv1.y, bv1.z, bv1.w};
#pragma unroll
  for (int q = 0; q < 8; ++q) {
    const float cell = (v[q] - mean) * isc;
    an[q] = 0.99f * ai[q] + 0.01f * cell;
    bn[q] = bi[q] + an[q];
  }
  *(float4*)ap = {an[0], an[1], an[2], an[3]};
  *(float4*)(ap + 4) = {an[4], an[5], an[6], an[7]};
  *(float4*)bp = {bn[0], bn[1], bn[2], bn[3]};
  *(float4*)(bp + 4) = {bn[4], bn[5], bn[6], bn[7]};
  if (!last) {
    float hv[8];
#pragma unroll
    for (int q = 0; q < 8; ++q) hv[q] = bn[q] + fe_val(f0 + q);
    const int lo = pk4f8(hv[0], hv[1], hv[2], hv[3]);
    const int hi = pk4f8(hv[4], hv[5], hv[6], hv[7]);
    *(int2*)((u8*)outp + (long)col * F_ + f0) = {lo, hi};
  } else {
    bf8 oa, ob;
#pragma unroll
    for (int q = 0; q < 8; ++q) {
      oa[q] = (__bf16)an[q];
      ob[q] = (__bf16)bn[q];
    }
    *(bf8*)((__bf16*)outp + (long)col * (2 * F_) + f0) = oa;
    *(bf8*)((__bf16*)outp + (long)col * (2 * F_) + F_ + f0) = ob;
  }
}

// Fused logits GEMM (bf16) + bias + softmax + NLL. 32-position tiles,
// grid (64, 2) = 128 blocks for 2x parallelism vs R6.
__global__ __launch_bounds__(256) void k_logits_nll(
    const __bf16* __restrict__ A, const __bf16* __restrict__ Bb,
    const float* __restrict__ outb, const int* __restrict__ tgt,
    float* __restrict__ acc) {
  __shared__ __bf16 As[256 * 32];
  __shared__ __bf16 Bs[32 * 32];
  __shared__ float lsm[32 * 256];
  const int tid = threadIdx.x;
  const int b = blockIdx.y;
  const int n0 = blockIdx.x * 32;
  const __bf16* Bt = Bb + (long)b * (S_ * 2 * F_) + (long)n0 * (2 * F_);
  const int lane = tid & 63;
  const int wave = tid >> 6;
  const int l15 = lane & 15;
  const int quad = lane >> 4;
  const int cr = tid >> 2;
  const int csw = (((tid & 3) ^ ((cr >> 1) & 3)) << 3);
  const int roff = ((quad ^ ((l15 >> 1) & 3)) << 3);
  f4 av[4][2] = {};
  for (int k0 = 0; k0 < 2 * F_; k0 += 32) {
#pragma unroll
    for (int i = 0; i < 4; ++i)
      gload_lds16(A + (long)(i * 64 + cr) * (2 * F_) + (k0 + csw),
                  As + ((i * 256 + (wave << 6)) << 3));
    if (wave < 2)
      gload_lds16(Bt + (long)cr * (2 * F_) + (k0 + csw),
                  Bs + ((wave << 6) << 3));
    __syncthreads();
    bf8 af[4], bfr[2];
#pragma unroll
    for (int mt = 0; mt < 4; ++mt)
      af[mt] = *(const bf8*)(As + (wave * 64 + mt * 16 + l15) * 32 + roff);
#pragma unroll
    for (int nt = 0; nt < 2; ++nt)
      bfr[nt] = *(const bf8*)(Bs + (nt * 16 + l15) * 32 + roff);
#pragma unroll
    for (int mt = 0; mt < 4; ++mt)
#pragma unroll
      for (int nt = 0; nt < 2; ++nt)
        av[mt][nt] = __builtin_amdgcn_mfma_f32_16x16x32_bf16(af[mt], bfr[nt],
                                                             av[mt][nt], 0, 0, 0);
    __syncthreads();
  }
#pragma unroll
  for (int mt = 0; mt < 4; ++mt) {
    const int m = wave * 64 + mt * 16 + quad * 4;
#pragma unroll
    for (int nt = 0; nt < 2; ++nt) {
      const int pp = nt * 16 + l15;
      *(f4*)(lsm + pp * C_ + m) = av[mt][nt];
    }
  }
  __syncthreads();
  const float4 bv = *(const float4*)(outb + lane * 4);
  float wsum = 0.f;
  for (int i = 0; i < 8; ++i) {
    const int pp = wave * 8 + i;
    const f4 lv = *(const f4*)(lsm + pp * C_ + lane * 4);
    const float x0 = lv[0] + bv.x, x1 = lv[1] + bv.y, x2 = lv[2] + bv.z,
                x3 = lv[3] + bv.w;
    float mx = fmaxf(fmaxf(x0, x1), fmaxf(x2, x3));
#pragma unroll
    for (int off = 1; off < 64; off <<= 1) mx = fmaxf(mx, __shfl_xor(mx, off));
    float ss = expf(x0 - mx) + expf(x1 - mx) + expf(x2 - mx) + expf(x3 - mx);
#pragma unroll
    for (int off = 1; off < 64; off <<= 1) ss += __shfl_xor(ss, off);
    if (lane == 0) {
      const int t = tgt[b * S_ + n0 + pp];
      wsum += mx + logf(ss) - (lsm[pp * C_ + t] + outb[t]);
    }
  }
  if (lane == 0) atomicAdd(acc, wsum);
}

__global__ void k_final(const float* __restrict__ acc, float* __restrict__ out) {
  out[0] = acc[0] * (1.0f / 4096.0f);
}

extern "C" void kernel_launch(void* const* d_in, const int* in_sizes, int n_in,
                              void* d_out, int out_size, void* d_ws,
                              size_t ws_size, hipStream_t stream) {
  const int* inp = (const int*)d_in[0];
  const int* tgt = (const int*)d_in[1];
  const float* emb = (const float*)d_in[2];
  const float* w0s = (const float*)d_in[3];
  const float* w1s = (const float*)d_in[4];
  const float* w2s = (const float*)d_in[5];
  const float* out_w = (const float*)d_in[6];
  const float* out_b = (const float*)d_in[7];

  char* ws = (char*)d_ws;
  float* acc = (float*)(ws + 0);
  u8* zp = (u8*)(ws + 256);
  float* a_st = (float*)(ws + 4096);
  float* b_st = (float*)(ws + 8392704L);
  u8* h = (u8*)(ws + 16781312L);            // [b*2048+s][512] fp8
  u8* Y1f8 = (u8*)(ws + 20975616L);         // [b][s][3072] fp8
  u8* Y2f8 = (u8*)(ws + 46141440L);         // [b*3+p][s][1024] fp8
  float* Y3 = (float*)(ws + 71307264L);     // [b*3+p][s][512] f32
  u8* W1f8 = (u8*)(ws + 96473088L);         // [(l*3+p)*I+i][3072] fp8 x64
  __bf16* streams = (__bf16*)(ws + 134221824L);
  u8* W0f8 = (u8*)(ws + 146804736L);        // [l][3072][512] fp8 x64
  u8* W2f8 = (u8*)(ws + 153096192L);        // [l][3*512][1024] fp8 x64
  __bf16* OWc = (__bf16*)(ws + 159387648L);

  hipMemsetAsync(ws, 0, 4096, stream);  // acc + zero page
  k_prep<<<12544, 256, 0, stream>>>(w0s, w2s, out_w, w1s, W0f8, W2f8, OWc, W1f8);
  k_embed<<<4096, 64, 0, stream>>>(inp, emb, a_st, b_st, h);

  for (int l = 0; l < 2; ++l) {
    // conv1: (3I x F) @ h -> Y1 fp8, relu
    gemm_f8<1, true, 2, 128, 512, 512><<<dim3(16, 24, 2), 256, 0, stream>>>(
        W0f8 + (long)l * 1572864L, h, Y1f8, zp, 3072, 1, 0L, 0L, 1048576L,
        6291456L);
    // conv2: causal k=3 (I x 3I) -> Y2 fp8, relu
    gemm_f8<3, true, 2, 128, 1024, 3072><<<dim3(16, 8, 6), 256, 0, stream>>>(
        W1f8 + (long)l * 9437184L, Y1f8, Y2f8, zp, 1024, 3, 3145728L, 1024L,
        6291456L, 2097152L);
    // conv3: (F x I) @ Y2 -> Y3 f32
    gemm_f8<1, false, 0, 64, 1024, 1024><<<dim3(32, 4, 6), 256, 0, stream>>>(
        W2f8 + (long)l * 1572864L, Y2f8, Y3, zp, 512, 3, 524288L, 2097152L,
        6291456L, 1048576L);
    k_cell<<<4096, 64, 0, stream>>>(Y3, a_st, b_st,
                                    (l == 0) ? (void*)h : (void*)streams,
                                    (l == 1) ? 1 : 0);
  }

  k_logits_nll<<<dim3(64, 2), 256, 0, stream>>>(OWc, streams, out_b, tgt, acc);
  k_final<<<1, 1, 0, stream>>>(acc, (float*)d_out);
}